// Round 8
// baseline (270.234 us; speedup 1.0000x reference)
//
#include <hip/hip_runtime.h>
#include <hip/hip_bf16.h>
#include <math.h>

#define LN_EPS 1e-5f

typedef __attribute__((ext_vector_type(8))) short bf16x8;
typedef __attribute__((ext_vector_type(8))) short short8;
typedef __attribute__((ext_vector_type(4))) float f32x4;
typedef unsigned short ushort_t;

__device__ __forceinline__ float silu_f(float x) {
    return x / (1.0f + __expf(-x));
}

__device__ __forceinline__ ushort_t f2bf(float f) {
    __hip_bfloat16 h = __float2bfloat16(f);
    return *reinterpret_cast<ushort_t*>(&h);
}

__device__ __forceinline__ float bf2f(ushort_t u) {
    __hip_bfloat16 h = *reinterpret_cast<__hip_bfloat16*>(&u);
    return __bfloat162float(h);
}

// pack two f32 -> one dword of 2 bf16 (lo = a, hi = b). gfx950 has no
// cvt_pk_bf16 builtin (m240) -- guarantee the single-instruction form.
__device__ __forceinline__ unsigned pk2(float a, float b) {
    unsigned r;
    asm("v_cvt_pk_bf16_f32 %0, %1, %2" : "=v"(r) : "v"(a), "v"(b));
    return r;
}

// exp2 guaranteed as single v_exp_f32.
__device__ __forceinline__ float fast_exp2(float x) {
#if defined(__has_builtin)
#if __has_builtin(__builtin_amdgcn_exp2f)
    return __builtin_amdgcn_exp2f(x);
#else
    return exp2f(x);
#endif
#else
    return exp2f(x);
#endif
}

// async global->LDS 16B per lane. lds must be wave-uniform; dst = lds + lane*16.
__device__ __forceinline__ void gld16(const void* g, void* lds) {
    __builtin_amdgcn_global_load_lds(
        (const __attribute__((address_space(1))) unsigned int*)g,
        (__attribute__((address_space(3))) unsigned int*)lds, 16, 0, 0);
}

// Block-wide reduction of (sum, sumsq). blockDim.x == 256 (4 waves of 64).
__device__ __forceinline__ float2 block_reduce2(float2 p, float2* sbuf) {
    #pragma unroll
    for (int off = 32; off > 0; off >>= 1) {
        p.x += __shfl_down(p.x, off, 64);
        p.y += __shfl_down(p.y, off, 64);
    }
    int lane = threadIdx.x & 63;
    int wid  = threadIdx.x >> 6;
    if (lane == 0) sbuf[wid] = p;
    __syncthreads();
    if (threadIdx.x == 0) {
        float2 r = sbuf[0];
        for (int i = 1; i < 4; ++i) { r.x += sbuf[i].x; r.y += sbuf[i].y; }
        sbuf[0] = r;
    }
    __syncthreads();
    return sbuf[0];
}

// ---------------------------------------------------------------------------
// LN (no affine) + SiLU, fp32 in -> bf16 out. One block per row of 1024.
// ---------------------------------------------------------------------------
__global__ __launch_bounds__(256) void ln_silu_kernel(
    const float* __restrict__ x, ushort_t* __restrict__ out)
{
    __shared__ float2 sbuf[4];
    const int C = 1024;
    int row = blockIdx.x;
    const float4* xr = (const float4*)(x + (size_t)row * C);
    float4 v = xr[threadIdx.x];
    float2 p;
    p.x = v.x + v.y + v.z + v.w;
    p.y = v.x*v.x + v.y*v.y + v.z*v.z + v.w*v.w;
    float2 s = block_reduce2(p, sbuf);
    float mean = s.x / (float)C;
    float var  = s.y / (float)C - mean * mean;
    float rstd = rsqrtf(var + LN_EPS);
    ushort4 y;
    y.x = f2bf(silu_f((v.x - mean) * rstd));
    y.y = f2bf(silu_f((v.y - mean) * rstd));
    y.z = f2bf(silu_f((v.z - mean) * rstd));
    y.w = f2bf(silu_f((v.w - mean) * rstd));
    ((ushort4*)(out + (size_t)row * C))[threadIdx.x] = y;
}

// ---------------------------------------------------------------------------
// Affine LN in place on bf16 rows of 1024, then scale. grid.y selects q/k.
// ---------------------------------------------------------------------------
__global__ __launch_bounds__(256) void ln_affine_bf16(
    ushort_t* __restrict__ qk0, ushort_t* __restrict__ qk1,
    const float* __restrict__ g0, const float* __restrict__ be0,
    const float* __restrict__ g1, const float* __restrict__ be1,
    float scale0, float scale1)
{
    __shared__ float2 sbuf[4];
    const int C = 1024;
    int which = blockIdx.y;
    ushort_t* q = which ? qk1 : qk0;
    const float* g  = which ? g1  : g0;
    const float* be = which ? be1 : be0;
    float scale = which ? scale1 : scale0;
    int row = blockIdx.x;
    ushort4 u = ((ushort4*)(q + (size_t)row * C))[threadIdx.x];
    float v0 = bf2f(u.x), v1 = bf2f(u.y), v2 = bf2f(u.z), v3 = bf2f(u.w);
    float2 p;
    p.x = v0 + v1 + v2 + v3;
    p.y = v0*v0 + v1*v1 + v2*v2 + v3*v3;
    float2 s = block_reduce2(p, sbuf);
    float mean = s.x / (float)C;
    float var  = s.y / (float)C - mean * mean;
    float rstd = rsqrtf(var + LN_EPS);
    float4 gv = ((const float4*)g)[threadIdx.x];
    float4 bv = ((const float4*)be)[threadIdx.x];
    ushort4 y;
    y.x = f2bf(((v0 - mean) * rstd * gv.x + bv.x) * scale);
    y.y = f2bf(((v1 - mean) * rstd * gv.y + bv.y) * scale);
    y.z = f2bf(((v2 - mean) * rstd * gv.z + bv.z) * scale);
    y.w = f2bf(((v3 - mean) * rstd * gv.w + bv.w) * scale);
    ((ushort4*)(q + (size_t)row * C))[threadIdx.x] = y;
}

// ---------------------------------------------------------------------------
// Transpose 4 fp32 weight matrices [1024][1024] -> bf16 [N][K] (W^T).
// ---------------------------------------------------------------------------
struct W4 { const float* p[4]; };

__global__ __launch_bounds__(256) void transpose_w(W4 w, ushort_t* __restrict__ outbase)
{
    __shared__ float Ls[64][65];
    int z = blockIdx.z;
    const float* in = w.p[z];
    ushort_t* out = outbase + (size_t)z * 1024 * 1024;
    int r0 = blockIdx.y * 64, c0 = blockIdx.x * 64;
    int t = threadIdx.x, r = t >> 2, j = (t & 3) * 16;
    #pragma unroll
    for (int i = 0; i < 4; ++i) {
        float4 v = *(const float4*)(in + (size_t)(r0 + r) * 1024 + c0 + j + i * 4);
        Ls[r][j + i*4 + 0] = v.x;
        Ls[r][j + i*4 + 1] = v.y;
        Ls[r][j + i*4 + 2] = v.z;
        Ls[r][j + i*4 + 3] = v.w;
    }
    __syncthreads();
    __align__(16) ushort_t tmp[16];
    #pragma unroll
    for (int i = 0; i < 16; ++i) tmp[i] = f2bf(Ls[j + i][r]);
    ushort_t* op = out + (size_t)(c0 + r) * 1024 + r0 + j;
    *(short8*)(op)     = *(short8*)(tmp);
    *(short8*)(op + 8) = *(short8*)(tmp + 8);
}

// ---------------------------------------------------------------------------
// bf16 MFMA GEMM: C[M,N] = A[M,K] @ Bt[N,K]^T + bias.
// BM x 128 tile, BK=64, 256 threads (4 waves, 2x2), 16x16x32 MFMA.
// Pipelined double-buffered staging (counted vmcnt, raw s_barrier).
// T1 XCD swizzle: bijective chunked remap for L2 locality.
// z-grid selects weight/bias (fused QKV). z==2 (V) writes V^T
// [b][channel][token] via a wave-local LDS transpose.
// ---------------------------------------------------------------------------
template<int BM, bool OUT_BF16>
__global__ __launch_bounds__(256) void gemm_mfma(
    const ushort_t* __restrict__ A, const ushort_t* __restrict__ Bt0,
    const float* __restrict__ b0, const float* __restrict__ b1,
    const float* __restrict__ b2, void* __restrict__ out0,
    ushort_t* __restrict__ vt_out,
    int M, int N, int K)
{
    constexpr int BK = 64;
    constexpr int MI = BM / 32;            // m-tiles of 16 per wave
    __shared__ ushort_t Smem[2 * (BM + 128) * BK];
    ushort_t* As0 = Smem;                          // [BM][64]
    ushort_t* Bs0 = Smem + BM * BK;                // [128][64]
    ushort_t* As1 = Smem + (BM + 128) * BK;
    ushort_t* Bs1 = As1 + BM * BK;

    // T1 XCD swizzle. Launch geometry is fixed: BM=128 -> grid (8,32,3),
    // BM=64 -> grid (8,64,1). NB % 8 == 0 in both cases (bijective).
    constexpr int NY = (BM == 128) ? 32 : 64;
    constexpr int NZ = (BM == 128) ? 3 : 1;
    constexpr int NB = 8 * NY * NZ;
    constexpr int CHUNK = NB / 8;
    int lin = blockIdx.x + 8 * (blockIdx.y + NY * blockIdx.z);
    int swz = (lin & 7) * CHUNK + (lin >> 3);
    int bx = swz & 7;
    int by = (swz >> 3) & (NY - 1);
    int z  = swz / (8 * NY);

    const ushort_t* Bt = Bt0 + (size_t)z * N * K;
    const float* bias = (z == 0) ? b0 : (z == 1) ? b1 : b2;

    int t = threadIdx.x;
    int lane = t & 63, wv = t >> 6;
    int wr = wv >> 1, wc = wv & 1;
    int quad = lane >> 4, ln16 = lane & 15;

    int row0 = by * BM;
    int col0 = bx * 128;

    const f32x4 zero4 = {0.f, 0.f, 0.f, 0.f};
    f32x4 acc[MI][4];
    #pragma unroll
    for (int i = 0; i < MI; ++i)
        #pragma unroll
        for (int j = 0; j < 4; ++j) acc[i][j] = zero4;

    auto stage = [&](ushort_t* AsB, ushort_t* BsB, int kt) {
        #pragma unroll
        for (int c = 0; c < BM / 32; ++c) {
            int idx = c * 256 + t;
            int r = idx >> 3, ch = idx & 7;
            int g = ch ^ (r & 7);
            gld16(A + (size_t)(row0 + r) * K + kt + g * 8,
                  AsB + (size_t)(c * 256 + wv * 64) * 8);
        }
        #pragma unroll
        for (int c = 0; c < 4; ++c) {
            int idx = c * 256 + t;
            int r = idx >> 3, ch = idx & 7;
            int g = ch ^ (r & 7);
            gld16(Bt + (size_t)(col0 + r) * K + kt + g * 8,
                  BsB + (size_t)(c * 256 + wv * 64) * 8);
        }
    };

    auto compute = [&](const ushort_t* AsB, const ushort_t* BsB) {
        #pragma unroll
        for (int s = 0; s < 2; ++s) {
            bf16x8 af[MI], bf[4];
            int g = s * 4 + quad;
            #pragma unroll
            for (int i = 0; i < MI; ++i) {
                int m = wr * (BM / 2) + i * 16 + ln16;
                af[i] = *(const bf16x8*)(AsB + (size_t)(m * 8 + (g ^ (m & 7))) * 8);
            }
            #pragma unroll
            for (int j = 0; j < 4; ++j) {
                int n = wc * 64 + j * 16 + ln16;
                bf[j] = *(const bf16x8*)(BsB + (size_t)(n * 8 + (g ^ (n & 7))) * 8);
            }
            __builtin_amdgcn_s_setprio(1);
            #pragma unroll
            for (int i = 0; i < MI; ++i)
                #pragma unroll
                for (int j = 0; j < 4; ++j)
                    acc[i][j] = __builtin_amdgcn_mfma_f32_16x16x32_bf16(
                        af[i], bf[j], acc[i][j], 0, 0, 0);
            __builtin_amdgcn_s_setprio(0);
        }
    };

    auto wait_prev = [&]() {   // tile t's LOADS landed; next tile stays in flight
        if constexpr (BM == 128) asm volatile("s_waitcnt vmcnt(8)" ::: "memory");
        else                     asm volatile("s_waitcnt vmcnt(6)" ::: "memory");
    };

    const int NTk = K / BK;                // 16 (K=1024), even
    stage(As0, Bs0, 0);
    #pragma unroll 1
    for (int it = 0; it < NTk; it += 2) {
        // phase A: compute buf0 (tile it), prefetch tile it+1 into buf1
        stage(As1, Bs1, (it + 1) * BK);    // buf1 reads finished last phase
        wait_prev();
        __builtin_amdgcn_s_barrier();
        __builtin_amdgcn_sched_barrier(0);
        compute(As0, Bs0);
        __builtin_amdgcn_sched_barrier(0);
        __builtin_amdgcn_s_barrier();

        // phase B: compute buf1 (tile it+1), prefetch tile it+2 into buf0
        if (it + 2 < NTk) {
            stage(As0, Bs0, (it + 2) * BK);
            wait_prev();
        } else {
            asm volatile("s_waitcnt vmcnt(0)" ::: "memory");
        }
        __builtin_amdgcn_s_barrier();
        __builtin_amdgcn_sched_barrier(0);
        compute(As1, Bs1);
        __builtin_amdgcn_sched_barrier(0);
        __builtin_amdgcn_s_barrier();
    }

    if (OUT_BF16 && z == 2 && BM == 128) {
        // V^T epilogue: transpose each wave's 64tok x 64ch tile via its own
        // 8KB LDS region (wave-local, no barrier; loop-exit barrier already
        // drained all LDS reads), then coalesced [channel][token] stores.
        ushort_t* tb = Smem + wv * 4096;           // 64 rows x 64 ushorts
        int tok0 = row0 + wr * 64;
        int chn0 = col0 + wc * 64;
        #pragma unroll
        for (int j = 0; j < 4; ++j) {
            int chl = j * 16 + ln16;
            float bv = bias[chn0 + chl];
            #pragma unroll
            for (int i = 0; i < MI; ++i) {
                uint2 uu;
                uu.x = pk2(acc[i][j][0] + bv, acc[i][j][1] + bv);
                uu.y = pk2(acc[i][j][2] + bv, acc[i][j][3] + bv);
                int hc = i * 4 + quad;                  // 8B half-chunk (tok/4)
                int phys = hc ^ ((chl & 7) << 1);       // keeps 16B pairs intact
                *(uint2*)(tb + chl * 64 + phys * 4) = uu;
            }
        }
        int bb2 = tok0 >> 11;
        int tokb = tok0 & 2047;
        #pragma unroll
        for (int p = 0; p < 8; ++p) {
            int chl = p * 8 + (lane >> 3);
            int tc  = lane & 7;
            int ptc = tc ^ (chl & 7);
            uint4 vvv = *(const uint4*)(tb + chl * 64 + ptc * 8);
            *(uint4*)(vt_out + ((size_t)bb2 * 1024 + chn0 + chl) * 2048 + tokb + tc * 8) = vvv;
        }
    } else {
        #pragma unroll
        for (int j = 0; j < 4; ++j) {
            int col = col0 + wc * 64 + j * 16 + ln16;
            float bv = bias[col];
            #pragma unroll
            for (int i = 0; i < MI; ++i) {
                int rowb = row0 + wr * (BM / 2) + i * 16 + quad * 4;
                #pragma unroll
                for (int r = 0; r < 4; ++r) {
                    float val = acc[i][j][r] + bv;
                    if (OUT_BF16) {
                        ushort_t* out = (ushort_t*)out0 + (size_t)z * M * N;
                        out[(size_t)(rowb + r) * N + col] = f2bf(val);
                    } else {
                        float* out = (float*)out0;
                        out[(size_t)(rowb + r) * N + col] = val;
                    }
                }
            }
        }
    }
}

// ---------------------------------------------------------------------------
// MFMA flash attention, S^T formulation, register-resident P, STATIC softmax,
// K=32 PV, T15 two-tile pipeline, KT=64 double-buffered K/V, counted vmcnt,
// T1 XCD swizzle (all carried from R7).
//
// KEY-SPLIT (this round, retry of R5 with FLAT NAMED registers -- R5's 2D
// f32x4 arrays were demoted to scratch, WRITE_SIZE 171MB, mechanism never
// tested): the 4 waves form a 2x2 (q-half, key-half) grid. Wave (qh,kh)
// computes q-rows qh*32..+31 (2 groups of 16) x keys kh*32..+31 of EVERY
// tile. Each K/V LDS fragment read feeds 2 MFMAs (the 2 q-groups), halving
// per-wave ds_read traffic (16 -> 8 b128/tile) at IDENTICAL grid (1024,
// 4 blocks/CU), block q-coverage (64 rows), MFMA count, and exp2 count --
// isolating the LDS-bandwidth variable (R1's attempt confounded it with an
// occupancy halving). Partial O/l combined through 17KB of dead K/V LDS at
// the epilogue (kh=1 publishes, kh=0 finalizes).
//
// All per-tile state is scalar-named (rule #20): sA/B{u}{qg}, o{qg}{mt} --
// no arrays anywhere in the hot path.
// q pre-scaled by inner^-0.5 * log2(e); static m=0 softmax (scores bounded).
// l accumulated on the matrix pipe via ones-MFMA. O accumulates transposed
// (O^T[d][qrow=ln16]); epilogue fuses SiLU -> packed bf16.
// ---------------------------------------------------------------------------
__global__ __launch_bounds__(256, 4) void flash_mfma(
    const ushort_t* __restrict__ qb, const ushort_t* __restrict__ kb,
    const ushort_t* __restrict__ vT, ushort_t* __restrict__ ob)
{
    const int N = 2048, HD = 1024, D = 64, H = 16;
    const int KT = 64;                     // keys per tile
    const int NT = N / KT;                 // 32 tiles
    __shared__ ushort_t Ks[2][64 * 64];    // [buf][perm-pos][d], 8-chunk xor swizzle
    __shared__ ushort_t Vs[2][64 * 64];    // [buf][d][token], 8-chunk xor swizzle

    int t = threadIdx.x, lane = t & 63, wv = t >> 6;
    int quad = lane >> 4, ln16 = lane & 15;
    int qh = wv & 1, kh = wv >> 1;         // q-half, key-half of this wave
    // T1 XCD swizzle: lin -> chunked remap (1024 = 8 XCDs x 128 chunks).
    int lin = blockIdx.x + 32 * (blockIdx.y + 16 * blockIdx.z);
    int swz = ((lin & 7) << 7) + (lin >> 3);
    int qt = swz & 31, h = (swz >> 5) & 15, b = swz >> 9;

    size_t qk_base = (size_t)b * N * HD + (size_t)h * D;
    size_t vt_base = (size_t)(b * H + h) * D * N;

    // Q fragments (B-operand, K=32) for the wave's 2 groups of 16 q-rows.
    bf16x8 qf0a, qf0b, qf1a, qf1b;
    {
        const ushort_t* qp0 = qb + qk_base +
            (size_t)(qt * 64 + qh * 32 + ln16) * HD;
        qf0a = *(const bf16x8*)(qp0 + quad * 8);
        qf0b = *(const bf16x8*)(qp0 + 32 + quad * 8);
        const ushort_t* qp1 = qp0 + (size_t)16 * HD;
        qf1a = *(const bf16x8*)(qp1 + quad * 8);
        qf1b = *(const bf16x8*)(qp1 + 32 + quad * 8);
    }

    // ones fragment (bf16 1.0) for the l-accumulating MFMA.
    bf16x8 ones;
    #pragma unroll
    for (int i = 0; i < 8; ++i) ones[i] = (short)0x3F80;

    const f32x4 zero4 = {0.f, 0.f, 0.f, 0.f};
    f32x4 o00 = zero4, o01 = zero4, o02 = zero4, o03 = zero4;   // qg0, mt 0..3
    f32x4 o10 = zero4, o11 = zero4, o12 = zero4, o13 = zero4;   // qg1
    f32x4 lac0 = zero4, lac1 = zero4;

    // ---- staging: 2 gld16 per thread per K-tile / V-tile -------------------
    auto stage_K = [&](ushort_t* KsB, int kt) {
        #pragma unroll
        for (int c = 0; c < 2; ++c) {
            int idx = c * 256 + t;
            int r = idx >> 3, ch = idx & 7, g = ch ^ (r & 7);
            // K row permutation: LDS pos r holds key perm(r)
            int pr = (r & ~31) | (((r >> 2) & 3) << 3) | (((r >> 4) & 1) << 2) | (r & 3);
            gld16(kb + qk_base + (size_t)(kt + pr) * HD + g * 8,
                  KsB + (size_t)(c * 256 + wv * 64) * 8);
        }
    };
    auto stage_V = [&](ushort_t* VsB, int kt) {
        #pragma unroll
        for (int c = 0; c < 2; ++c) {
            int idx = c * 256 + t;
            int r = idx >> 3, ch = idx & 7, g = ch ^ (r & 7);
            gld16(vT + vt_base + (size_t)r * N + kt + g * 8,
                  VsB + (size_t)(c * 256 + wv * 64) * 8);
        }
    };

    // ---- QK^T: this wave's 32 keys x its 32 q-rows -------------------------
    // Position rows n = kh*32 + u*16 + ln16 (u = 16-key subtile). s=0 passes
    // zero4 directly as C-in (no per-tile zero-init movs).
    auto qk_tile = [&](const ushort_t* KsB,
                       f32x4& s0q0, f32x4& s0q1, f32x4& s1q0, f32x4& s1q1) {
        int n0 = kh * 32 + ln16;
        int n1 = n0 + 16;
        __builtin_amdgcn_s_setprio(1);
        {
            bf16x8 kf0 = *(const bf16x8*)(KsB + ((size_t)n0 * 8 + (quad ^ (n0 & 7))) * 8);
            bf16x8 kf1 = *(const bf16x8*)(KsB + ((size_t)n1 * 8 + (quad ^ (n1 & 7))) * 8);
            s0q0 = __builtin_amdgcn_mfma_f32_16x16x32_bf16(kf0, qf0a, zero4, 0, 0, 0);
            s0q1 = __builtin_amdgcn_mfma_f32_16x16x32_bf16(kf0, qf1a, zero4, 0, 0, 0);
            s1q0 = __builtin_amdgcn_mfma_f32_16x16x32_bf16(kf1, qf0a, zero4, 0, 0, 0);
            s1q1 = __builtin_amdgcn_mfma_f32_16x16x32_bf16(kf1, qf1a, zero4, 0, 0, 0);
        }
        {
            int g = 4 + quad;
            bf16x8 kf0 = *(const bf16x8*)(KsB + ((size_t)n0 * 8 + (g ^ (n0 & 7))) * 8);
            bf16x8 kf1 = *(const bf16x8*)(KsB + ((size_t)n1 * 8 + (g ^ (n1 & 7))) * 8);
            s0q0 = __builtin_amdgcn_mfma_f32_16x16x32_bf16(kf0, qf0b, s0q0, 0, 0, 0);
            s0q1 = __builtin_amdgcn_mfma_f32_16x16x32_bf16(kf0, qf1b, s0q1, 0, 0, 0);
            s1q0 = __builtin_amdgcn_mfma_f32_16x16x32_bf16(kf1, qf0b, s1q0, 0, 0, 0);
            s1q1 = __builtin_amdgcn_mfma_f32_16x16x32_bf16(kf1, qf1b, s1q1, 0, 0, 0);
        }
        __builtin_amdgcn_s_setprio(0);
    };

    // ---- softmax + PV of one tile (scores from a PREVIOUS qk_tile) ---------
    auto sm_pv = [&](f32x4& s0q0, f32x4& s0q1, f32x4& s1q0, f32x4& s1q1,
                     const ushort_t* VsB) {
        // prefetch this key-half's 4 V fragments; reused by both q-groups.
        int phys = (kh * 4 + quad) ^ (ln16 & 7);
        bf16x8 vf0 = *(const bf16x8*)(VsB + (size_t)(ln16)      * 64 + phys * 8);
        bf16x8 vf1 = *(const bf16x8*)(VsB + (size_t)(16 + ln16) * 64 + phys * 8);
        bf16x8 vf2 = *(const bf16x8*)(VsB + (size_t)(32 + ln16) * 64 + phys * 8);
        bf16x8 vf3 = *(const bf16x8*)(VsB + (size_t)(48 + ln16) * 64 + phys * 8);
        // static softmax: p = exp2(s) (q pre-scaled by log2 e).
        s0q0[0] = fast_exp2(s0q0[0]); s0q0[1] = fast_exp2(s0q0[1]);
        s0q0[2] = fast_exp2(s0q0[2]); s0q0[3] = fast_exp2(s0q0[3]);
        s0q1[0] = fast_exp2(s0q1[0]); s0q1[1] = fast_exp2(s0q1[1]);
        s0q1[2] = fast_exp2(s0q1[2]); s0q1[3] = fast_exp2(s0q1[3]);
        s1q0[0] = fast_exp2(s1q0[0]); s1q0[1] = fast_exp2(s1q0[1]);
        s1q0[2] = fast_exp2(s1q0[2]); s1q0[3] = fast_exp2(s1q0[3]);
        s1q1[0] = fast_exp2(s1q1[0]); s1q1[1] = fast_exp2(s1q1[1]);
        s1q1[2] = fast_exp2(s1q1[2]); s1q1[3] = fast_exp2(s1q1[3]);
        // pack P fragments (keys 32*kh + 8*quad + 0..7 per lane).
        uint4 up0, up1;
        up0.x = pk2(s0q0[0], s0q0[1]); up0.y = pk2(s0q0[2], s0q0[3]);
        up0.z = pk2(s1q0[0], s1q0[1]); up0.w = pk2(s1q0[2], s1q0[3]);
        up1.x = pk2(s0q1[0], s0q1[1]); up1.y = pk2(s0q1[2], s0q1[3]);
        up1.z = pk2(s1q1[0], s1q1[1]); up1.w = pk2(s1q1[2], s1q1[3]);
        bf16x8 pf0 = __builtin_bit_cast(bf16x8, up0);
        bf16x8 pf1 = __builtin_bit_cast(bf16x8, up1);
        // O^T += V^T @ P (K=32, this wave's keys); l += 1 @ P on matrix pipe.
        __builtin_amdgcn_s_setprio(1);
        lac0 = __builtin_amdgcn_mfma_f32_16x16x32_bf16(ones, pf0, lac0, 0, 0, 0);
        lac1 = __builtin_amdgcn_mfma_f32_16x16x32_bf16(ones, pf1, lac1, 0, 0, 0);
        o00 = __builtin_amdgcn_mfma_f32_16x16x32_bf16(vf0, pf0, o00, 0, 0, 0);
        o10 = __builtin_amdgcn_mfma_f32_16x16x32_bf16(vf0, pf1, o10, 0, 0, 0);
        o01 = __builtin_amdgcn_mfma_f32_16x16x32_bf16(vf1, pf0, o01, 0, 0, 0);
        o11 = __builtin_amdgcn_mfma_f32_16x16x32_bf16(vf1, pf1, o11, 0, 0, 0);
        o02 = __builtin_amdgcn_mfma_f32_16x16x32_bf16(vf2, pf0, o02, 0, 0, 0);
        o12 = __builtin_amdgcn_mfma_f32_16x16x32_bf16(vf2, pf1, o12, 0, 0, 0);
        o03 = __builtin_amdgcn_mfma_f32_16x16x32_bf16(vf3, pf0, o03, 0, 0, 0);
        o13 = __builtin_amdgcn_mfma_f32_16x16x32_bf16(vf3, pf1, o13, 0, 0, 0);
        __builtin_amdgcn_s_setprio(0);
    };

    f32x4 sA0q0, sA0q1, sA1q0, sA1q1;      // score state A
    f32x4 sB0q0, sB0q1, sB1q0, sB1q1;      // score state B

    // ---- prologue: stage tiles 0,1; compute S(0) ---------------------------
    stage_K(Ks[0], 0);       stage_V(Vs[0], 0);
    stage_K(Ks[1], KT);      stage_V(Vs[1], KT);
    asm volatile("s_waitcnt vmcnt(4)" ::: "memory");   // tile0 K&V landed
    __builtin_amdgcn_s_barrier();
    __builtin_amdgcn_sched_barrier(0);
    qk_tile(Ks[0], sA0q0, sA0q1, sA1q0, sA1q1);        // S(0)
    __builtin_amdgcn_sched_barrier(0);
    __builtin_amdgcn_s_barrier();                      // all S(0) reads done

    // ---- main loop: phases t = 0..NT-3 (unroll 2, static buffers) ----------
    #pragma unroll 1
    for (int it = 0; it < NT - 2; it += 2) {
        // t = it (even): consume stA/Vs[0], produce stB = S(it+1) from Ks[1]
        stage_K(Ks[0], (it + 2) * KT);                 // K(t) reads done last phase
        asm volatile("s_waitcnt vmcnt(4)" ::: "memory"); // K(it+1), V(it) landed
        __builtin_amdgcn_s_barrier();
        __builtin_amdgcn_sched_barrier(0);
        qk_tile(Ks[1], sB0q0, sB0q1, sB1q0, sB1q1);    // S(it+1), no dep on stA
        sm_pv(sA0q0, sA0q1, sA1q0, sA1q1, Vs[0]);      // finish tile it
        __builtin_amdgcn_sched_barrier(0);
        __builtin_amdgcn_s_barrier();                  // all reads this phase done
        stage_V(Vs[0], (it + 2) * KT);                 // V(it) dead -> reuse

        // t = it+1 (odd): consume stB/Vs[1], produce stA = S(it+2) from Ks[0]
        stage_K(Ks[1], (it + 3) * KT);
        asm volatile("s_waitcnt vmcnt(4)" ::: "memory"); // K(it+2), V(it+1) landed
        __builtin_amdgcn_s_barrier();
        __builtin_amdgcn_sched_barrier(0);
        qk_tile(Ks[0], sA0q0, sA0q1, sA1q0, sA1q1);    // S(it+2)
        sm_pv(sB0q0, sB0q1, sB1q0, sB1q1, Vs[1]);      // finish tile it+1
        __builtin_amdgcn_sched_barrier(0);
        __builtin_amdgcn_s_barrier();
        stage_V(Vs[1], (it + 3) * KT);
    }

    // ---- tail: t = NT-2 (=30) and t = NT-1 (=31) ---------------------------
    asm volatile("s_waitcnt vmcnt(2)" ::: "memory");   // V(30), K(31) landed
    __builtin_amdgcn_s_barrier();
    __builtin_amdgcn_sched_barrier(0);
    qk_tile(Ks[1], sB0q0, sB0q1, sB1q0, sB1q1);        // S(31)
    sm_pv(sA0q0, sA0q1, sA1q0, sA1q1, Vs[0]);          // tile 30
    asm volatile("s_waitcnt vmcnt(0)" ::: "memory");   // V(31) landed
    __builtin_amdgcn_s_barrier();
    __builtin_amdgcn_sched_barrier(0);
    sm_pv(sB0q0, sB0q1, sB1q0, sB1q1, Vs[1]);          // tile 31

    // ---- epilogue: combine key-halves, then SiLU + packed bf16 stores ------
    // kh=1 waves publish partial O (16KB, dead Ks region) + l (dead Vs
    // region); kh=0 waves add their partials, normalize, activate, store.
    __syncthreads();                                   // all K/V LDS reads done
    float* obufL = (float*)Ks;   // [(qh*2+qg)*4 + mt] regions of 64 lanes x f32x4
    float* lbufL = (float*)Vs;   // [(qh*2+qg)*64 + lane]
    if (kh == 1) {
        int r0 = (qh * 2 + 0) * 4;
        *(f32x4*)(obufL + ((r0 + 0) * 64 + lane) * 4) = o00;
        *(f32x4*)(obufL + ((r0 + 1) * 64 + lane) * 4) = o01;
        *(f32x4*)(obufL + ((r0 + 2) * 64 + lane) * 4) = o02;
        *(f32x4*)(obufL + ((r0 + 3) * 64 + lane) * 4) = o03;
        int r1 = (qh * 2 + 1) * 4;
        *(f32x4*)(obufL + ((r1 + 0) * 64 + lane) * 4) = o10;
        *(f32x4*)(obufL + ((r1 + 1) * 64 + lane) * 4) = o11;
        *(f32x4*)(obufL + ((r1 + 2) * 64 + lane) * 4) = o12;
        *(f32x4*)(obufL + ((r1 + 3) * 64 + lane) * 4) = o13;
        lbufL[(qh * 2 + 0) * 64 + lane] = lac0[0];
        lbufL[(qh * 2 + 1) * 64 + lane] = lac1[0];
    }
    __syncthreads();
    if (kh == 0) {
        size_t rowoff0 = qk_base + (size_t)(qt * 64 + qh * 32 + ln16) * HD;
        #define FIN(OV, MT, RG, ROFF, LINV) { \
            f32x4 p = *(const f32x4*)(obufL + (((RG) + (MT)) * 64 + lane) * 4); \
            float f0 = silu_f((OV[0] + p[0]) * (LINV)); \
            float f1 = silu_f((OV[1] + p[1]) * (LINV)); \
            float f2 = silu_f((OV[2] + p[2]) * (LINV)); \
            float f3 = silu_f((OV[3] + p[3]) * (LINV)); \
            uint2 uu; uu.x = pk2(f0, f1); uu.y = pk2(f2, f3); \
            *(uint2*)(ob + (ROFF) + (MT) * 16 + quad * 4) = uu; }
        {
            float l = lac0[0] + lbufL[(qh * 2 + 0) * 64 + lane];
            float inv = 1.0f / l;
            int r0 = (qh * 2 + 0) * 4;
            FIN(o00, 0, r0, rowoff0, inv);
            FIN(o01, 1, r0, rowoff0, inv);
            FIN(o02, 2, r0, rowoff0, inv);
            FIN(o03, 3, r0, rowoff0, inv);
        }
        {
            float l = lac1[0] + lbufL[(qh * 2 + 1) * 64 + lane];
            float inv = 1.0f / l;
            int r1 = (qh * 2 + 1) * 4;
            size_t rowoff1 = rowoff0 + (size_t)16 * HD;
            FIN(o10, 0, r1, rowoff1, inv);
            FIN(o11, 1, r1, rowoff1, inv);
            FIN(o12, 2, r1, rowoff1, inv);
            FIN(o13, 3, r1, rowoff1, inv);
        }
        #undef FIN
    }
}

// ---------------------------------------------------------------------------
extern "C" void kernel_launch(void* const* d_in, const int* in_sizes, int n_in,
                              void* d_out, int out_size, void* d_ws, size_t ws_size,
                              hipStream_t stream) {
    const float* x    = (const float*)d_in[0];
    const float* w_q  = (const float*)d_in[1];
    const float* b_q  = (const float*)d_in[2];
    const float* w_k  = (const float*)d_in[3];
    const float* b_k  = (const float*)d_in[4];
    const float* w_v  = (const float*)d_in[5];
    const float* b_v  = (const float*)d_in[6];
    const float* g_q  = (const float*)d_in[7];
    const float* be_q = (const float*)d_in[8];
    const float* g_k  = (const float*)d_in[9];
    const float* be_k = (const float*)d_in[10];
    const float* w_o  = (const float*)d_in[11];
    const float* b_o  = (const float*)d_in[12];
    float* out = (float*)d_out;

    const int B = 2, N = 2048, C = 1024, H = 16, INNER = 1024;
    const int M = B * N;                       // 4096
    const size_t MC = (size_t)M * C;           // 4194304

    // ws layout (ushort elems): sx | qkv(3x, v slot unused) | vT | wT(4x)
    ushort_t* ws  = (ushort_t*)d_ws;
    ushort_t* sx  = ws;                        // [M][1024] bf16 (later reused as o)
    ushort_t* qkv = ws + MC;                   // [3][M][1024]
    ushort_t* vTp = ws + 4 * MC;               // [B][1024][2048] natural key order
    ushort_t* wT  = ws + 5 * MC;               // [4][1024][1024]

    ushort_t* qbuf = qkv;
    ushort_t* kbuf = qkv + MC;
    ushort_t* obuf = sx;                       // sx dead after QKV GEMM

    // 1. weight transposes fp32 [K][N] -> bf16 [N][K]
    W4 w4; w4.p[0] = w_q; w4.p[1] = w_k; w4.p[2] = w_v; w4.p[3] = w_o;
    transpose_w<<<dim3(16, 16, 4), 256, 0, stream>>>(w4, wT);

    // 2. pre-norm + SiLU -> bf16
    ln_silu_kernel<<<M, 256, 0, stream>>>(x, sx);

    // 3. fused QKV GEMM (q/k bf16 rows; v written as natural-order V^T)
    gemm_mfma<128, true><<<dim3(INNER / 128, M / 128, 3), 256, 0, stream>>>(
        sx, wT, b_q, b_k, b_v, qkv, vTp, M, INNER, C);

    // 4. q/k layernorms (bf16 in place); q scaled by inner^-0.5 * log2(e)
    //    (softmax computed in base 2 -> identical weights)
    ln_affine_bf16<<<dim3(M, 2), 256, 0, stream>>>(
        qbuf, kbuf, g_q, be_q, g_k, be_k, 0.03125f * 1.44269504f, 1.0f);

    // 5. flash attention (writes silu(o) bf16 into obuf), 64 Q-rows/block
    flash_mfma<<<dim3(N / 64, H, B), 256, 0, stream>>>(qbuf, kbuf, vTp, obuf);

    // 6. final GEMM -> fp32 out
    gemm_mfma<64, false><<<dim3(C / 128, M / 64, 1), 256, 0, stream>>>(
        obuf, wT + (size_t)3 * 1024 * 1024, b_o, b_o, b_o, out, nullptr, M, C, INNER);
}

// Round 9
// 206.267 us; speedup vs baseline: 1.3101x; 1.3101x over previous
//
#include <hip/hip_runtime.h>
#include <hip/hip_bf16.h>
#include <math.h>

#define LN_EPS 1e-5f

typedef __attribute__((ext_vector_type(8))) short bf16x8;
typedef __attribute__((ext_vector_type(8))) short short8;
typedef __attribute__((ext_vector_type(4))) float f32x4;
typedef unsigned short ushort_t;

__device__ __forceinline__ float silu_f(float x) {
    return x / (1.0f + __expf(-x));
}

__device__ __forceinline__ ushort_t f2bf(float f) {
    __hip_bfloat16 h = __float2bfloat16(f);
    return *reinterpret_cast<ushort_t*>(&h);
}

__device__ __forceinline__ float bf2f(ushort_t u) {
    __hip_bfloat16 h = *reinterpret_cast<__hip_bfloat16*>(&u);
    return __bfloat162float(h);
}

// pack two f32 -> one dword of 2 bf16 (lo = a, hi = b). gfx950 has no
// cvt_pk_bf16 builtin (m240) -- guarantee the single-instruction form.
__device__ __forceinline__ unsigned pk2(float a, float b) {
    unsigned r;
    asm("v_cvt_pk_bf16_f32 %0, %1, %2" : "=v"(r) : "v"(a), "v"(b));
    return r;
}

// exp2 guaranteed as single v_exp_f32.
__device__ __forceinline__ float fast_exp2(float x) {
#if defined(__has_builtin)
#if __has_builtin(__builtin_amdgcn_exp2f)
    return __builtin_amdgcn_exp2f(x);
#else
    return exp2f(x);
#endif
#else
    return exp2f(x);
#endif
}

// async global->LDS 16B per lane. lds must be wave-uniform; dst = lds + lane*16.
__device__ __forceinline__ void gld16(const void* g, void* lds) {
    __builtin_amdgcn_global_load_lds(
        (const __attribute__((address_space(1))) unsigned int*)g,
        (__attribute__((address_space(3))) unsigned int*)lds, 16, 0, 0);
}

// Block-wide reduction of (sum, sumsq). blockDim.x == 256 (4 waves of 64).
__device__ __forceinline__ float2 block_reduce2(float2 p, float2* sbuf) {
    #pragma unroll
    for (int off = 32; off > 0; off >>= 1) {
        p.x += __shfl_down(p.x, off, 64);
        p.y += __shfl_down(p.y, off, 64);
    }
    int lane = threadIdx.x & 63;
    int wid  = threadIdx.x >> 6;
    if (lane == 0) sbuf[wid] = p;
    __syncthreads();
    if (threadIdx.x == 0) {
        float2 r = sbuf[0];
        for (int i = 1; i < 4; ++i) { r.x += sbuf[i].x; r.y += sbuf[i].y; }
        sbuf[0] = r;
    }
    __syncthreads();
    return sbuf[0];
}

// ---------------------------------------------------------------------------
// LN (no affine) + SiLU, fp32 in -> bf16 out. One block per row of 1024.
// ---------------------------------------------------------------------------
__global__ __launch_bounds__(256) void ln_silu_kernel(
    const float* __restrict__ x, ushort_t* __restrict__ out)
{
    __shared__ float2 sbuf[4];
    const int C = 1024;
    int row = blockIdx.x;
    const float4* xr = (const float4*)(x + (size_t)row * C);
    float4 v = xr[threadIdx.x];
    float2 p;
    p.x = v.x + v.y + v.z + v.w;
    p.y = v.x*v.x + v.y*v.y + v.z*v.z + v.w*v.w;
    float2 s = block_reduce2(p, sbuf);
    float mean = s.x / (float)C;
    float var  = s.y / (float)C - mean * mean;
    float rstd = rsqrtf(var + LN_EPS);
    ushort4 y;
    y.x = f2bf(silu_f((v.x - mean) * rstd));
    y.y = f2bf(silu_f((v.y - mean) * rstd));
    y.z = f2bf(silu_f((v.z - mean) * rstd));
    y.w = f2bf(silu_f((v.w - mean) * rstd));
    ((ushort4*)(out + (size_t)row * C))[threadIdx.x] = y;
}

// ---------------------------------------------------------------------------
// Affine LN in place on bf16 rows of 1024, then scale. grid.y selects q/k.
// ---------------------------------------------------------------------------
__global__ __launch_bounds__(256) void ln_affine_bf16(
    ushort_t* __restrict__ qk0, ushort_t* __restrict__ qk1,
    const float* __restrict__ g0, const float* __restrict__ be0,
    const float* __restrict__ g1, const float* __restrict__ be1,
    float scale0, float scale1)
{
    __shared__ float2 sbuf[4];
    const int C = 1024;
    int which = blockIdx.y;
    ushort_t* q = which ? qk1 : qk0;
    const float* g  = which ? g1  : g0;
    const float* be = which ? be1 : be0;
    float scale = which ? scale1 : scale0;
    int row = blockIdx.x;
    ushort4 u = ((ushort4*)(q + (size_t)row * C))[threadIdx.x];
    float v0 = bf2f(u.x), v1 = bf2f(u.y), v2 = bf2f(u.z), v3 = bf2f(u.w);
    float2 p;
    p.x = v0 + v1 + v2 + v3;
    p.y = v0*v0 + v1*v1 + v2*v2 + v3*v3;
    float2 s = block_reduce2(p, sbuf);
    float mean = s.x / (float)C;
    float var  = s.y / (float)C - mean * mean;
    float rstd = rsqrtf(var + LN_EPS);
    float4 gv = ((const float4*)g)[threadIdx.x];
    float4 bv = ((const float4*)be)[threadIdx.x];
    ushort4 y;
    y.x = f2bf(((v0 - mean) * rstd * gv.x + bv.x) * scale);
    y.y = f2bf(((v1 - mean) * rstd * gv.y + bv.y) * scale);
    y.z = f2bf(((v2 - mean) * rstd * gv.z + bv.z) * scale);
    y.w = f2bf(((v3 - mean) * rstd * gv.w + bv.w) * scale);
    ((ushort4*)(q + (size_t)row * C))[threadIdx.x] = y;
}

// ---------------------------------------------------------------------------
// Transpose 4 fp32 weight matrices [1024][1024] -> bf16 [N][K] (W^T).
// ---------------------------------------------------------------------------
struct W4 { const float* p[4]; };

__global__ __launch_bounds__(256) void transpose_w(W4 w, ushort_t* __restrict__ outbase)
{
    __shared__ float Ls[64][65];
    int z = blockIdx.z;
    const float* in = w.p[z];
    ushort_t* out = outbase + (size_t)z * 1024 * 1024;
    int r0 = blockIdx.y * 64, c0 = blockIdx.x * 64;
    int t = threadIdx.x, r = t >> 2, j = (t & 3) * 16;
    #pragma unroll
    for (int i = 0; i < 4; ++i) {
        float4 v = *(const float4*)(in + (size_t)(r0 + r) * 1024 + c0 + j + i * 4);
        Ls[r][j + i*4 + 0] = v.x;
        Ls[r][j + i*4 + 1] = v.y;
        Ls[r][j + i*4 + 2] = v.z;
        Ls[r][j + i*4 + 3] = v.w;
    }
    __syncthreads();
    __align__(16) ushort_t tmp[16];
    #pragma unroll
    for (int i = 0; i < 16; ++i) tmp[i] = f2bf(Ls[j + i][r]);
    ushort_t* op = out + (size_t)(c0 + r) * 1024 + r0 + j;
    *(short8*)(op)     = *(short8*)(tmp);
    *(short8*)(op + 8) = *(short8*)(tmp + 8);
}

// ---------------------------------------------------------------------------
// bf16 MFMA GEMM: C[M,N] = A[M,K] @ Bt[N,K]^T + bias.
// BM x 128 tile, BK=64, 256 threads (4 waves, 2x2), 16x16x32 MFMA.
// Pipelined double-buffered staging (counted vmcnt, raw s_barrier).
// T1 XCD swizzle: bijective chunked remap for L2 locality.
// z-grid selects weight/bias (fused QKV). z==2 (V) writes V^T
// [b][channel][token] via a wave-local LDS transpose.
// ---------------------------------------------------------------------------
template<int BM, bool OUT_BF16>
__global__ __launch_bounds__(256) void gemm_mfma(
    const ushort_t* __restrict__ A, const ushort_t* __restrict__ Bt0,
    const float* __restrict__ b0, const float* __restrict__ b1,
    const float* __restrict__ b2, void* __restrict__ out0,
    ushort_t* __restrict__ vt_out,
    int M, int N, int K)
{
    constexpr int BK = 64;
    constexpr int MI = BM / 32;            // m-tiles of 16 per wave
    __shared__ ushort_t Smem[2 * (BM + 128) * BK];
    ushort_t* As0 = Smem;                          // [BM][64]
    ushort_t* Bs0 = Smem + BM * BK;                // [128][64]
    ushort_t* As1 = Smem + (BM + 128) * BK;
    ushort_t* Bs1 = As1 + BM * BK;

    // T1 XCD swizzle. Launch geometry is fixed: BM=128 -> grid (8,32,3),
    // BM=64 -> grid (8,64,1). NB % 8 == 0 in both cases (bijective).
    constexpr int NY = (BM == 128) ? 32 : 64;
    constexpr int NZ = (BM == 128) ? 3 : 1;
    constexpr int NB = 8 * NY * NZ;
    constexpr int CHUNK = NB / 8;
    int lin = blockIdx.x + 8 * (blockIdx.y + NY * blockIdx.z);
    int swz = (lin & 7) * CHUNK + (lin >> 3);
    int bx = swz & 7;
    int by = (swz >> 3) & (NY - 1);
    int z  = swz / (8 * NY);

    const ushort_t* Bt = Bt0 + (size_t)z * N * K;
    const float* bias = (z == 0) ? b0 : (z == 1) ? b1 : b2;

    int t = threadIdx.x;
    int lane = t & 63, wv = t >> 6;
    int wr = wv >> 1, wc = wv & 1;
    int quad = lane >> 4, ln16 = lane & 15;

    int row0 = by * BM;
    int col0 = bx * 128;

    const f32x4 zero4 = {0.f, 0.f, 0.f, 0.f};
    f32x4 acc[MI][4];
    #pragma unroll
    for (int i = 0; i < MI; ++i)
        #pragma unroll
        for (int j = 0; j < 4; ++j) acc[i][j] = zero4;

    auto stage = [&](ushort_t* AsB, ushort_t* BsB, int kt) {
        #pragma unroll
        for (int c = 0; c < BM / 32; ++c) {
            int idx = c * 256 + t;
            int r = idx >> 3, ch = idx & 7;
            int g = ch ^ (r & 7);
            gld16(A + (size_t)(row0 + r) * K + kt + g * 8,
                  AsB + (size_t)(c * 256 + wv * 64) * 8);
        }
        #pragma unroll
        for (int c = 0; c < 4; ++c) {
            int idx = c * 256 + t;
            int r = idx >> 3, ch = idx & 7;
            int g = ch ^ (r & 7);
            gld16(Bt + (size_t)(col0 + r) * K + kt + g * 8,
                  BsB + (size_t)(c * 256 + wv * 64) * 8);
        }
    };

    auto compute = [&](const ushort_t* AsB, const ushort_t* BsB) {
        #pragma unroll
        for (int s = 0; s < 2; ++s) {
            bf16x8 af[MI], bf[4];
            int g = s * 4 + quad;
            #pragma unroll
            for (int i = 0; i < MI; ++i) {
                int m = wr * (BM / 2) + i * 16 + ln16;
                af[i] = *(const bf16x8*)(AsB + (size_t)(m * 8 + (g ^ (m & 7))) * 8);
            }
            #pragma unroll
            for (int j = 0; j < 4; ++j) {
                int n = wc * 64 + j * 16 + ln16;
                bf[j] = *(const bf16x8*)(BsB + (size_t)(n * 8 + (g ^ (n & 7))) * 8);
            }
            __builtin_amdgcn_s_setprio(1);
            #pragma unroll
            for (int i = 0; i < MI; ++i)
                #pragma unroll
                for (int j = 0; j < 4; ++j)
                    acc[i][j] = __builtin_amdgcn_mfma_f32_16x16x32_bf16(
                        af[i], bf[j], acc[i][j], 0, 0, 0);
            __builtin_amdgcn_s_setprio(0);
        }
    };

    auto wait_prev = [&]() {   // tile t's LOADS landed; next tile stays in flight
        if constexpr (BM == 128) asm volatile("s_waitcnt vmcnt(8)" ::: "memory");
        else                     asm volatile("s_waitcnt vmcnt(6)" ::: "memory");
    };

    const int NTk = K / BK;                // 16 (K=1024), even
    stage(As0, Bs0, 0);
    #pragma unroll 1
    for (int it = 0; it < NTk; it += 2) {
        // phase A: compute buf0 (tile it), prefetch tile it+1 into buf1
        stage(As1, Bs1, (it + 1) * BK);    // buf1 reads finished last phase
        wait_prev();
        __builtin_amdgcn_s_barrier();
        __builtin_amdgcn_sched_barrier(0);
        compute(As0, Bs0);
        __builtin_amdgcn_sched_barrier(0);
        __builtin_amdgcn_s_barrier();

        // phase B: compute buf1 (tile it+1), prefetch tile it+2 into buf0
        if (it + 2 < NTk) {
            stage(As0, Bs0, (it + 2) * BK);
            wait_prev();
        } else {
            asm volatile("s_waitcnt vmcnt(0)" ::: "memory");
        }
        __builtin_amdgcn_s_barrier();
        __builtin_amdgcn_sched_barrier(0);
        compute(As1, Bs1);
        __builtin_amdgcn_sched_barrier(0);
        __builtin_amdgcn_s_barrier();
    }

    if (OUT_BF16 && z == 2 && BM == 128) {
        // V^T epilogue: transpose each wave's 64tok x 64ch tile via its own
        // 8KB LDS region (wave-local, no barrier; loop-exit barrier already
        // drained all LDS reads), then coalesced [channel][token] stores.
        ushort_t* tb = Smem + wv * 4096;           // 64 rows x 64 ushorts
        int tok0 = row0 + wr * 64;
        int chn0 = col0 + wc * 64;
        #pragma unroll
        for (int j = 0; j < 4; ++j) {
            int chl = j * 16 + ln16;
            float bv = bias[chn0 + chl];
            #pragma unroll
            for (int i = 0; i < MI; ++i) {
                uint2 uu;
                uu.x = pk2(acc[i][j][0] + bv, acc[i][j][1] + bv);
                uu.y = pk2(acc[i][j][2] + bv, acc[i][j][3] + bv);
                int hc = i * 4 + quad;                  // 8B half-chunk (tok/4)
                int phys = hc ^ ((chl & 7) << 1);       // keeps 16B pairs intact
                *(uint2*)(tb + chl * 64 + phys * 4) = uu;
            }
        }
        int bb2 = tok0 >> 11;
        int tokb = tok0 & 2047;
        #pragma unroll
        for (int p = 0; p < 8; ++p) {
            int chl = p * 8 + (lane >> 3);
            int tc  = lane & 7;
            int ptc = tc ^ (chl & 7);
            uint4 vvv = *(const uint4*)(tb + chl * 64 + ptc * 8);
            *(uint4*)(vt_out + ((size_t)bb2 * 1024 + chn0 + chl) * 2048 + tokb + tc * 8) = vvv;
        }
    } else {
        #pragma unroll
        for (int j = 0; j < 4; ++j) {
            int col = col0 + wc * 64 + j * 16 + ln16;
            float bv = bias[col];
            #pragma unroll
            for (int i = 0; i < MI; ++i) {
                int rowb = row0 + wr * (BM / 2) + i * 16 + quad * 4;
                #pragma unroll
                for (int r = 0; r < 4; ++r) {
                    float val = acc[i][j][r] + bv;
                    if (OUT_BF16) {
                        ushort_t* out = (ushort_t*)out0 + (size_t)z * M * N;
                        out[(size_t)(rowb + r) * N + col] = f2bf(val);
                    } else {
                        float* out = (float*)out0;
                        out[(size_t)(rowb + r) * N + col] = val;
                    }
                }
            }
        }
    }
}

// ---------------------------------------------------------------------------
// MFMA flash attention, S^T formulation, register-resident P, STATIC softmax,
// K=32 PV, T15 two-tile pipeline, KT=64 double-buffered K/V, counted vmcnt,
// T1 XCD swizzle, key-split 2x2 (q-half, key-half) wave grid -- R8 body.
//
// THIS ROUND (single change): __launch_bounds__(256, 2) instead of (256, 4).
// Session ledger shows hipcc caps VGPRs at 64 when the 2nd arg is 4 for
// 256-thread blocks (R0-R8: every arg=4 build reports <=64 VGPR; R8 needed
// ~115 live and SPILLED at 64 -- WRITE_SIZE 207MB; the one arg=2 build (R2)
// reported 72). arg=2 raises the cap to ~128. Occupancy is unchanged in
// practice: ~115 VGPR -> 4 waves/SIMD still fit, LDS 32KB -> 4 blocks/CU,
// and the grid (1024 = 4/CU) binds either way. This finally tests the
// key-split LDS-halving mechanism without the spill confound.
// ---------------------------------------------------------------------------
__global__ __launch_bounds__(256, 2) void flash_mfma(
    const ushort_t* __restrict__ qb, const ushort_t* __restrict__ kb,
    const ushort_t* __restrict__ vT, ushort_t* __restrict__ ob)
{
    const int N = 2048, HD = 1024, D = 64, H = 16;
    const int KT = 64;                     // keys per tile
    const int NT = N / KT;                 // 32 tiles
    __shared__ ushort_t Ks[2][64 * 64];    // [buf][perm-pos][d], 8-chunk xor swizzle
    __shared__ ushort_t Vs[2][64 * 64];    // [buf][d][token], 8-chunk xor swizzle

    int t = threadIdx.x, lane = t & 63, wv = t >> 6;
    int quad = lane >> 4, ln16 = lane & 15;
    int qh = wv & 1, kh = wv >> 1;         // q-half, key-half of this wave
    // T1 XCD swizzle: lin -> chunked remap (1024 = 8 XCDs x 128 chunks).
    int lin = blockIdx.x + 32 * (blockIdx.y + 16 * blockIdx.z);
    int swz = ((lin & 7) << 7) + (lin >> 3);
    int qt = swz & 31, h = (swz >> 5) & 15, b = swz >> 9;

    size_t qk_base = (size_t)b * N * HD + (size_t)h * D;
    size_t vt_base = (size_t)(b * H + h) * D * N;

    // Q fragments (B-operand, K=32) for the wave's 2 groups of 16 q-rows.
    bf16x8 qf0a, qf0b, qf1a, qf1b;
    {
        const ushort_t* qp0 = qb + qk_base +
            (size_t)(qt * 64 + qh * 32 + ln16) * HD;
        qf0a = *(const bf16x8*)(qp0 + quad * 8);
        qf0b = *(const bf16x8*)(qp0 + 32 + quad * 8);
        const ushort_t* qp1 = qp0 + (size_t)16 * HD;
        qf1a = *(const bf16x8*)(qp1 + quad * 8);
        qf1b = *(const bf16x8*)(qp1 + 32 + quad * 8);
    }

    // ones fragment (bf16 1.0) for the l-accumulating MFMA.
    bf16x8 ones;
    #pragma unroll
    for (int i = 0; i < 8; ++i) ones[i] = (short)0x3F80;

    const f32x4 zero4 = {0.f, 0.f, 0.f, 0.f};
    f32x4 o00 = zero4, o01 = zero4, o02 = zero4, o03 = zero4;   // qg0, mt 0..3
    f32x4 o10 = zero4, o11 = zero4, o12 = zero4, o13 = zero4;   // qg1
    f32x4 lac0 = zero4, lac1 = zero4;

    // ---- staging: 2 gld16 per thread per K-tile / V-tile -------------------
    auto stage_K = [&](ushort_t* KsB, int kt) {
        #pragma unroll
        for (int c = 0; c < 2; ++c) {
            int idx = c * 256 + t;
            int r = idx >> 3, ch = idx & 7, g = ch ^ (r & 7);
            // K row permutation: LDS pos r holds key perm(r)
            int pr = (r & ~31) | (((r >> 2) & 3) << 3) | (((r >> 4) & 1) << 2) | (r & 3);
            gld16(kb + qk_base + (size_t)(kt + pr) * HD + g * 8,
                  KsB + (size_t)(c * 256 + wv * 64) * 8);
        }
    };
    auto stage_V = [&](ushort_t* VsB, int kt) {
        #pragma unroll
        for (int c = 0; c < 2; ++c) {
            int idx = c * 256 + t;
            int r = idx >> 3, ch = idx & 7, g = ch ^ (r & 7);
            gld16(vT + vt_base + (size_t)r * N + kt + g * 8,
                  VsB + (size_t)(c * 256 + wv * 64) * 8);
        }
    };

    // ---- QK^T: this wave's 32 keys x its 32 q-rows -------------------------
    // Position rows n = kh*32 + u*16 + ln16 (u = 16-key subtile). s=0 passes
    // zero4 directly as C-in (no per-tile zero-init movs).
    auto qk_tile = [&](const ushort_t* KsB,
                       f32x4& s0q0, f32x4& s0q1, f32x4& s1q0, f32x4& s1q1) {
        int n0 = kh * 32 + ln16;
        int n1 = n0 + 16;
        __builtin_amdgcn_s_setprio(1);
        {
            bf16x8 kf0 = *(const bf16x8*)(KsB + ((size_t)n0 * 8 + (quad ^ (n0 & 7))) * 8);
            bf16x8 kf1 = *(const bf16x8*)(KsB + ((size_t)n1 * 8 + (quad ^ (n1 & 7))) * 8);
            s0q0 = __builtin_amdgcn_mfma_f32_16x16x32_bf16(kf0, qf0a, zero4, 0, 0, 0);
            s0q1 = __builtin_amdgcn_mfma_f32_16x16x32_bf16(kf0, qf1a, zero4, 0, 0, 0);
            s1q0 = __builtin_amdgcn_mfma_f32_16x16x32_bf16(kf1, qf0a, zero4, 0, 0, 0);
            s1q1 = __builtin_amdgcn_mfma_f32_16x16x32_bf16(kf1, qf1a, zero4, 0, 0, 0);
        }
        {
            int g = 4 + quad;
            bf16x8 kf0 = *(const bf16x8*)(KsB + ((size_t)n0 * 8 + (g ^ (n0 & 7))) * 8);
            bf16x8 kf1 = *(const bf16x8*)(KsB + ((size_t)n1 * 8 + (g ^ (n1 & 7))) * 8);
            s0q0 = __builtin_amdgcn_mfma_f32_16x16x32_bf16(kf0, qf0b, s0q0, 0, 0, 0);
            s0q1 = __builtin_amdgcn_mfma_f32_16x16x32_bf16(kf0, qf1b, s0q1, 0, 0, 0);
            s1q0 = __builtin_amdgcn_mfma_f32_16x16x32_bf16(kf1, qf0b, s1q0, 0, 0, 0);
            s1q1 = __builtin_amdgcn_mfma_f32_16x16x32_bf16(kf1, qf1b, s1q1, 0, 0, 0);
        }
        __builtin_amdgcn_s_setprio(0);
    };

    // ---- softmax + PV of one tile (scores from a PREVIOUS qk_tile) ---------
    auto sm_pv = [&](f32x4& s0q0, f32x4& s0q1, f32x4& s1q0, f32x4& s1q1,
                     const ushort_t* VsB) {
        // prefetch this key-half's 4 V fragments; reused by both q-groups.
        int phys = (kh * 4 + quad) ^ (ln16 & 7);
        bf16x8 vf0 = *(const bf16x8*)(VsB + (size_t)(ln16)      * 64 + phys * 8);
        bf16x8 vf1 = *(const bf16x8*)(VsB + (size_t)(16 + ln16) * 64 + phys * 8);
        bf16x8 vf2 = *(const bf16x8*)(VsB + (size_t)(32 + ln16) * 64 + phys * 8);
        bf16x8 vf3 = *(const bf16x8*)(VsB + (size_t)(48 + ln16) * 64 + phys * 8);
        // static softmax: p = exp2(s) (q pre-scaled by log2 e).
        s0q0[0] = fast_exp2(s0q0[0]); s0q0[1] = fast_exp2(s0q0[1]);
        s0q0[2] = fast_exp2(s0q0[2]); s0q0[3] = fast_exp2(s0q0[3]);
        s0q1[0] = fast_exp2(s0q1[0]); s0q1[1] = fast_exp2(s0q1[1]);
        s0q1[2] = fast_exp2(s0q1[2]); s0q1[3] = fast_exp2(s0q1[3]);
        s1q0[0] = fast_exp2(s1q0[0]); s1q0[1] = fast_exp2(s1q0[1]);
        s1q0[2] = fast_exp2(s1q0[2]); s1q0[3] = fast_exp2(s1q0[3]);
        s1q1[0] = fast_exp2(s1q1[0]); s1q1[1] = fast_exp2(s1q1[1]);
        s1q1[2] = fast_exp2(s1q1[2]); s1q1[3] = fast_exp2(s1q1[3]);
        // pack P fragments (keys 32*kh + 8*quad + 0..7 per lane).
        uint4 up0, up1;
        up0.x = pk2(s0q0[0], s0q0[1]); up0.y = pk2(s0q0[2], s0q0[3]);
        up0.z = pk2(s1q0[0], s1q0[1]); up0.w = pk2(s1q0[2], s1q0[3]);
        up1.x = pk2(s0q1[0], s0q1[1]); up1.y = pk2(s0q1[2], s0q1[3]);
        up1.z = pk2(s1q1[0], s1q1[1]); up1.w = pk2(s1q1[2], s1q1[3]);
        bf16x8 pf0 = __builtin_bit_cast(bf16x8, up0);
        bf16x8 pf1 = __builtin_bit_cast(bf16x8, up1);
        // O^T += V^T @ P (K=32, this wave's keys); l += 1 @ P on matrix pipe.
        __builtin_amdgcn_s_setprio(1);
        lac0 = __builtin_amdgcn_mfma_f32_16x16x32_bf16(ones, pf0, lac0, 0, 0, 0);
        lac1 = __builtin_amdgcn_mfma_f32_16x16x32_bf16(ones, pf1, lac1, 0, 0, 0);
        o00 = __builtin_amdgcn_mfma_f32_16x16x32_bf16(vf0, pf0, o00, 0, 0, 0);
        o10 = __builtin_amdgcn_mfma_f32_16x16x32_bf16(vf0, pf1, o10, 0, 0, 0);
        o01 = __builtin_amdgcn_mfma_f32_16x16x32_bf16(vf1, pf0, o01, 0, 0, 0);
        o11 = __builtin_amdgcn_mfma_f32_16x16x32_bf16(vf1, pf1, o11, 0, 0, 0);
        o02 = __builtin_amdgcn_mfma_f32_16x16x32_bf16(vf2, pf0, o02, 0, 0, 0);
        o12 = __builtin_amdgcn_mfma_f32_16x16x32_bf16(vf2, pf1, o12, 0, 0, 0);
        o03 = __builtin_amdgcn_mfma_f32_16x16x32_bf16(vf3, pf0, o03, 0, 0, 0);
        o13 = __builtin_amdgcn_mfma_f32_16x16x32_bf16(vf3, pf1, o13, 0, 0, 0);
        __builtin_amdgcn_s_setprio(0);
    };

    f32x4 sA0q0, sA0q1, sA1q0, sA1q1;      // score state A
    f32x4 sB0q0, sB0q1, sB1q0, sB1q1;      // score state B

    // ---- prologue: stage tiles 0,1; compute S(0) ---------------------------
    stage_K(Ks[0], 0);       stage_V(Vs[0], 0);
    stage_K(Ks[1], KT);      stage_V(Vs[1], KT);
    asm volatile("s_waitcnt vmcnt(4)" ::: "memory");   // tile0 K&V landed
    __builtin_amdgcn_s_barrier();
    __builtin_amdgcn_sched_barrier(0);
    qk_tile(Ks[0], sA0q0, sA0q1, sA1q0, sA1q1);        // S(0)
    __builtin_amdgcn_sched_barrier(0);
    __builtin_amdgcn_s_barrier();                      // all S(0) reads done

    // ---- main loop: phases t = 0..NT-3 (unroll 2, static buffers) ----------
    #pragma unroll 1
    for (int it = 0; it < NT - 2; it += 2) {
        // t = it (even): consume stA/Vs[0], produce stB = S(it+1) from Ks[1]
        stage_K(Ks[0], (it + 2) * KT);                 // K(t) reads done last phase
        asm volatile("s_waitcnt vmcnt(4)" ::: "memory"); // K(it+1), V(it) landed
        __builtin_amdgcn_s_barrier();
        __builtin_amdgcn_sched_barrier(0);
        qk_tile(Ks[1], sB0q0, sB0q1, sB1q0, sB1q1);    // S(it+1), no dep on stA
        sm_pv(sA0q0, sA0q1, sA1q0, sA1q1, Vs[0]);      // finish tile it
        __builtin_amdgcn_sched_barrier(0);
        __builtin_amdgcn_s_barrier();                  // all reads this phase done
        stage_V(Vs[0], (it + 2) * KT);                 // V(it) dead -> reuse

        // t = it+1 (odd): consume stB/Vs[1], produce stA = S(it+2) from Ks[0]
        stage_K(Ks[1], (it + 3) * KT);
        asm volatile("s_waitcnt vmcnt(4)" ::: "memory"); // K(it+2), V(it+1) landed
        __builtin_amdgcn_s_barrier();
        __builtin_amdgcn_sched_barrier(0);
        qk_tile(Ks[0], sA0q0, sA0q1, sA1q0, sA1q1);    // S(it+2)
        sm_pv(sB0q0, sB0q1, sB1q0, sB1q1, Vs[1]);      // finish tile it+1
        __builtin_amdgcn_sched_barrier(0);
        __builtin_amdgcn_s_barrier();
        stage_V(Vs[1], (it + 3) * KT);
    }

    // ---- tail: t = NT-2 (=30) and t = NT-1 (=31) ---------------------------
    asm volatile("s_waitcnt vmcnt(2)" ::: "memory");   // V(30), K(31) landed
    __builtin_amdgcn_s_barrier();
    __builtin_amdgcn_sched_barrier(0);
    qk_tile(Ks[1], sB0q0, sB0q1, sB1q0, sB1q1);        // S(31)
    sm_pv(sA0q0, sA0q1, sA1q0, sA1q1, Vs[0]);          // tile 30
    asm volatile("s_waitcnt vmcnt(0)" ::: "memory");   // V(31) landed
    __builtin_amdgcn_s_barrier();
    __builtin_amdgcn_sched_barrier(0);
    sm_pv(sB0q0, sB0q1, sB1q0, sB1q1, Vs[1]);          // tile 31

    // ---- epilogue: combine key-halves, then SiLU + packed bf16 stores ------
    // kh=1 waves publish partial O (16KB, dead Ks region) + l (dead Vs
    // region); kh=0 waves add their partials, normalize, activate, store.
    __syncthreads();                                   // all K/V LDS reads done
    float* obufL = (float*)Ks;   // [(qh*2+qg)*4 + mt] regions of 64 lanes x f32x4
    float* lbufL = (float*)Vs;   // [(qh*2+qg)*64 + lane]
    if (kh == 1) {
        int r0 = (qh * 2 + 0) * 4;
        *(f32x4*)(obufL + ((r0 + 0) * 64 + lane) * 4) = o00;
        *(f32x4*)(obufL + ((r0 + 1) * 64 + lane) * 4) = o01;
        *(f32x4*)(obufL + ((r0 + 2) * 64 + lane) * 4) = o02;
        *(f32x4*)(obufL + ((r0 + 3) * 64 + lane) * 4) = o03;
        int r1 = (qh * 2 + 1) * 4;
        *(f32x4*)(obufL + ((r1 + 0) * 64 + lane) * 4) = o10;
        *(f32x4*)(obufL + ((r1 + 1) * 64 + lane) * 4) = o11;
        *(f32x4*)(obufL + ((r1 + 2) * 64 + lane) * 4) = o12;
        *(f32x4*)(obufL + ((r1 + 3) * 64 + lane) * 4) = o13;
        lbufL[(qh * 2 + 0) * 64 + lane] = lac0[0];
        lbufL[(qh * 2 + 1) * 64 + lane] = lac1[0];
    }
    __syncthreads();
    if (kh == 0) {
        size_t rowoff0 = qk_base + (size_t)(qt * 64 + qh * 32 + ln16) * HD;
        #define FIN(OV, MT, RG, ROFF, LINV) { \
            f32x4 p = *(const f32x4*)(obufL + (((RG) + (MT)) * 64 + lane) * 4); \
            float f0 = silu_f((OV[0] + p[0]) * (LINV)); \
            float f1 = silu_f((OV[1] + p[1]) * (LINV)); \
            float f2 = silu_f((OV[2] + p[2]) * (LINV)); \
            float f3 = silu_f((OV[3] + p[3]) * (LINV)); \
            uint2 uu; uu.x = pk2(f0, f1); uu.y = pk2(f2, f3); \
            *(uint2*)(ob + (ROFF) + (MT) * 16 + quad * 4) = uu; }
        {
            float l = lac0[0] + lbufL[(qh * 2 + 0) * 64 + lane];
            float inv = 1.0f / l;
            int r0 = (qh * 2 + 0) * 4;
            FIN(o00, 0, r0, rowoff0, inv);
            FIN(o01, 1, r0, rowoff0, inv);
            FIN(o02, 2, r0, rowoff0, inv);
            FIN(o03, 3, r0, rowoff0, inv);
        }
        {
            float l = lac1[0] + lbufL[(qh * 2 + 1) * 64 + lane];
            float inv = 1.0f / l;
            int r1 = (qh * 2 + 1) * 4;
            size_t rowoff1 = rowoff0 + (size_t)16 * HD;
            FIN(o10, 0, r1, rowoff1, inv);
            FIN(o11, 1, r1, rowoff1, inv);
            FIN(o12, 2, r1, rowoff1, inv);
            FIN(o13, 3, r1, rowoff1, inv);
        }
        #undef FIN
    }
}

// ---------------------------------------------------------------------------
extern "C" void kernel_launch(void* const* d_in, const int* in_sizes, int n_in,
                              void* d_out, int out_size, void* d_ws, size_t ws_size,
                              hipStream_t stream) {
    const float* x    = (const float*)d_in[0];
    const float* w_q  = (const float*)d_in[1];
    const float* b_q  = (const float*)d_in[2];
    const float* w_k  = (const float*)d_in[3];
    const float* b_k  = (const float*)d_in[4];
    const float* w_v  = (const float*)d_in[5];
    const float* b_v  = (const float*)d_in[6];
    const float* g_q  = (const float*)d_in[7];
    const float* be_q = (const float*)d_in[8];
    const float* g_k  = (const float*)d_in[9];
    const float* be_k = (const float*)d_in[10];
    const float* w_o  = (const float*)d_in[11];
    const float* b_o  = (const float*)d_in[12];
    float* out = (float*)d_out;

    const int B = 2, N = 2048, C = 1024, H = 16, INNER = 1024;
    const int M = B * N;                       // 4096
    const size_t MC = (size_t)M * C;           // 4194304

    // ws layout (ushort elems): sx | qkv(3x, v slot unused) | vT | wT(4x)
    ushort_t* ws  = (ushort_t*)d_ws;
    ushort_t* sx  = ws;                        // [M][1024] bf16 (later reused as o)
    ushort_t* qkv = ws + MC;                   // [3][M][1024]
    ushort_t* vTp = ws + 4 * MC;               // [B][1024][2048] natural key order
    ushort_t* wT  = ws + 5 * MC;               // [4][1024][1024]

    ushort_t* qbuf = qkv;
    ushort_t* kbuf = qkv + MC;
    ushort_t* obuf = sx;                       // sx dead after QKV GEMM

    // 1. weight transposes fp32 [K][N] -> bf16 [N][K]
    W4 w4; w4.p[0] = w_q; w4.p[1] = w_k; w4.p[2] = w_v; w4.p[3] = w_o;
    transpose_w<<<dim3(16, 16, 4), 256, 0, stream>>>(w4, wT);

    // 2. pre-norm + SiLU -> bf16
    ln_silu_kernel<<<M, 256, 0, stream>>>(x, sx);

    // 3. fused QKV GEMM (q/k bf16 rows; v written as natural-order V^T)
    gemm_mfma<128, true><<<dim3(INNER / 128, M / 128, 3), 256, 0, stream>>>(
        sx, wT, b_q, b_k, b_v, qkv, vTp, M, INNER, C);

    // 4. q/k layernorms (bf16 in place); q scaled by inner^-0.5 * log2(e)
    //    (softmax computed in base 2 -> identical weights)
    ln_affine_bf16<<<dim3(M, 2), 256, 0, stream>>>(
        qbuf, kbuf, g_q, be_q, g_k, be_k, 0.03125f * 1.44269504f, 1.0f);

    // 5. flash attention (writes silu(o) bf16 into obuf), 64 Q-rows/block
    flash_mfma<<<dim3(N / 64, H, B), 256, 0, stream>>>(qbuf, kbuf, vTp, obuf);

    // 6. final GEMM -> fp32 out
    gemm_mfma<64, false><<<dim3(C / 128, M / 64, 1), 256, 0, stream>>>(
        obuf, wT + (size_t)3 * 1024 * 1024, b_o, b_o, b_o, out, nullptr, M, C, INNER);
}

// Round 10
// 196.471 us; speedup vs baseline: 1.3754x; 1.0499x over previous
//
#include <hip/hip_runtime.h>
#include <hip/hip_bf16.h>
#include <math.h>

#define LN_EPS 1e-5f

typedef __attribute__((ext_vector_type(8))) short bf16x8;
typedef __attribute__((ext_vector_type(8))) short short8;
typedef __attribute__((ext_vector_type(4))) float f32x4;
typedef unsigned short ushort_t;

__device__ __forceinline__ float silu_f(float x) {
    return x / (1.0f + __expf(-x));
}

__device__ __forceinline__ ushort_t f2bf(float f) {
    __hip_bfloat16 h = __float2bfloat16(f);
    return *reinterpret_cast<ushort_t*>(&h);
}

__device__ __forceinline__ float bf2f(ushort_t u) {
    __hip_bfloat16 h = *reinterpret_cast<__hip_bfloat16*>(&u);
    return __bfloat162float(h);
}

// pack two f32 -> one dword of 2 bf16 (lo = a, hi = b). gfx950 has no
// cvt_pk_bf16 builtin (m240) -- guarantee the single-instruction form.
__device__ __forceinline__ unsigned pk2(float a, float b) {
    unsigned r;
    asm("v_cvt_pk_bf16_f32 %0, %1, %2" : "=v"(r) : "v"(a), "v"(b));
    return r;
}

// exp2 guaranteed as single v_exp_f32.
__device__ __forceinline__ float fast_exp2(float x) {
#if defined(__has_builtin)
#if __has_builtin(__builtin_amdgcn_exp2f)
    return __builtin_amdgcn_exp2f(x);
#else
    return exp2f(x);
#endif
#else
    return exp2f(x);
#endif
}

// async global->LDS 16B per lane. lds must be wave-uniform; dst = lds + lane*16.
__device__ __forceinline__ void gld16(const void* g, void* lds) {
    __builtin_amdgcn_global_load_lds(
        (const __attribute__((address_space(1))) unsigned int*)g,
        (__attribute__((address_space(3))) unsigned int*)lds, 16, 0, 0);
}

// Block-wide reduction of (sum, sumsq). blockDim.x == 256 (4 waves of 64).
__device__ __forceinline__ float2 block_reduce2(float2 p, float2* sbuf) {
    #pragma unroll
    for (int off = 32; off > 0; off >>= 1) {
        p.x += __shfl_down(p.x, off, 64);
        p.y += __shfl_down(p.y, off, 64);
    }
    int lane = threadIdx.x & 63;
    int wid  = threadIdx.x >> 6;
    if (lane == 0) sbuf[wid] = p;
    __syncthreads();
    if (threadIdx.x == 0) {
        float2 r = sbuf[0];
        for (int i = 1; i < 4; ++i) { r.x += sbuf[i].x; r.y += sbuf[i].y; }
        sbuf[0] = r;
    }
    __syncthreads();
    return sbuf[0];
}

// ---------------------------------------------------------------------------
// Fused prelude (this round): blocks 0..1023 transpose the 4 fp32 weight
// matrices [1024][1024] -> bf16 [N][K]; blocks 1024..5119 do LN(no affine)
// + SiLU on x rows (fp32 -> bf16). The two jobs are data-independent; one
// launch removes a dispatch gap and lets LN blocks fill the transpose tail.
// ---------------------------------------------------------------------------
struct W4 { const float* p[4]; };

__global__ __launch_bounds__(256) void prelude_kernel(
    W4 w, ushort_t* __restrict__ outbase,
    const float* __restrict__ x, ushort_t* __restrict__ xout)
{
    __shared__ float Ls[64][65];
    __shared__ float2 sbuf[4];
    int bid = blockIdx.x;
    int t = threadIdx.x;

    if (bid < 1024) {
        // ---- weight transpose: bid = z*256 + by*16 + bx ----
        int z = bid >> 8;
        const float* in = w.p[z];
        ushort_t* out = outbase + (size_t)z * 1024 * 1024;
        int r0 = ((bid >> 4) & 15) * 64, c0 = (bid & 15) * 64;
        int r = t >> 2, j = (t & 3) * 16;
        #pragma unroll
        for (int i = 0; i < 4; ++i) {
            float4 v = *(const float4*)(in + (size_t)(r0 + r) * 1024 + c0 + j + i * 4);
            Ls[r][j + i*4 + 0] = v.x;
            Ls[r][j + i*4 + 1] = v.y;
            Ls[r][j + i*4 + 2] = v.z;
            Ls[r][j + i*4 + 3] = v.w;
        }
        __syncthreads();
        __align__(16) ushort_t tmp[16];
        #pragma unroll
        for (int i = 0; i < 16; ++i) tmp[i] = f2bf(Ls[j + i][r]);
        ushort_t* op = out + (size_t)(c0 + r) * 1024 + r0 + j;
        *(short8*)(op)     = *(short8*)(tmp);
        *(short8*)(op + 8) = *(short8*)(tmp + 8);
    } else {
        // ---- LN + SiLU on one row of x ----
        const int C = 1024;
        int row = bid - 1024;
        const float4* xr = (const float4*)(x + (size_t)row * C);
        float4 v = xr[t];
        float2 p;
        p.x = v.x + v.y + v.z + v.w;
        p.y = v.x*v.x + v.y*v.y + v.z*v.z + v.w*v.w;
        float2 s = block_reduce2(p, sbuf);
        float mean = s.x / (float)C;
        float var  = s.y / (float)C - mean * mean;
        float rstd = rsqrtf(var + LN_EPS);
        ushort4 y;
        y.x = f2bf(silu_f((v.x - mean) * rstd));
        y.y = f2bf(silu_f((v.y - mean) * rstd));
        y.z = f2bf(silu_f((v.z - mean) * rstd));
        y.w = f2bf(silu_f((v.w - mean) * rstd));
        ((ushort4*)(xout + (size_t)row * C))[t] = y;
    }
}

// ---------------------------------------------------------------------------
// Affine LN in place on bf16 rows of 1024, then scale. grid.y selects q/k.
// ---------------------------------------------------------------------------
__global__ __launch_bounds__(256) void ln_affine_bf16(
    ushort_t* __restrict__ qk0, ushort_t* __restrict__ qk1,
    const float* __restrict__ g0, const float* __restrict__ be0,
    const float* __restrict__ g1, const float* __restrict__ be1,
    float scale0, float scale1)
{
    __shared__ float2 sbuf[4];
    const int C = 1024;
    int which = blockIdx.y;
    ushort_t* q = which ? qk1 : qk0;
    const float* g  = which ? g1  : g0;
    const float* be = which ? be1 : be0;
    float scale = which ? scale1 : scale0;
    int row = blockIdx.x;
    ushort4 u = ((ushort4*)(q + (size_t)row * C))[threadIdx.x];
    float v0 = bf2f(u.x), v1 = bf2f(u.y), v2 = bf2f(u.z), v3 = bf2f(u.w);
    float2 p;
    p.x = v0 + v1 + v2 + v3;
    p.y = v0*v0 + v1*v1 + v2*v2 + v3*v3;
    float2 s = block_reduce2(p, sbuf);
    float mean = s.x / (float)C;
    float var  = s.y / (float)C - mean * mean;
    float rstd = rsqrtf(var + LN_EPS);
    float4 gv = ((const float4*)g)[threadIdx.x];
    float4 bv = ((const float4*)be)[threadIdx.x];
    ushort4 y;
    y.x = f2bf(((v0 - mean) * rstd * gv.x + bv.x) * scale);
    y.y = f2bf(((v1 - mean) * rstd * gv.y + bv.y) * scale);
    y.z = f2bf(((v2 - mean) * rstd * gv.z + bv.z) * scale);
    y.w = f2bf(((v3 - mean) * rstd * gv.w + bv.w) * scale);
    ((ushort4*)(q + (size_t)row * C))[threadIdx.x] = y;
}

// ---------------------------------------------------------------------------
// bf16 MFMA GEMM: C[M,N] = A[M,K] @ Bt[N,K]^T + bias.
// BM x 128 tile, BK=64, 256 threads (4 waves, 2x2), 16x16x32 MFMA.
// Pipelined double-buffered staging (counted vmcnt, raw s_barrier).
// T1 XCD swizzle: bijective chunked remap for L2 locality.
// z-grid selects weight/bias (fused QKV). z==2 (V) writes V^T
// [b][channel][token] via a wave-local LDS transpose.
// ---------------------------------------------------------------------------
template<int BM, bool OUT_BF16>
__global__ __launch_bounds__(256) void gemm_mfma(
    const ushort_t* __restrict__ A, const ushort_t* __restrict__ Bt0,
    const float* __restrict__ b0, const float* __restrict__ b1,
    const float* __restrict__ b2, void* __restrict__ out0,
    ushort_t* __restrict__ vt_out,
    int M, int N, int K)
{
    constexpr int BK = 64;
    constexpr int MI = BM / 32;            // m-tiles of 16 per wave
    __shared__ ushort_t Smem[2 * (BM + 128) * BK];
    ushort_t* As0 = Smem;                          // [BM][64]
    ushort_t* Bs0 = Smem + BM * BK;                // [128][64]
    ushort_t* As1 = Smem + (BM + 128) * BK;
    ushort_t* Bs1 = As1 + BM * BK;

    // T1 XCD swizzle. Launch geometry is fixed: BM=128 -> grid (8,32,3),
    // BM=64 -> grid (8,64,1). NB % 8 == 0 in both cases (bijective).
    constexpr int NY = (BM == 128) ? 32 : 64;
    constexpr int NZ = (BM == 128) ? 3 : 1;
    constexpr int NB = 8 * NY * NZ;
    constexpr int CHUNK = NB / 8;
    int lin = blockIdx.x + 8 * (blockIdx.y + NY * blockIdx.z);
    int swz = (lin & 7) * CHUNK + (lin >> 3);
    int bx = swz & 7;
    int by = (swz >> 3) & (NY - 1);
    int z  = swz / (8 * NY);

    const ushort_t* Bt = Bt0 + (size_t)z * N * K;
    const float* bias = (z == 0) ? b0 : (z == 1) ? b1 : b2;

    int t = threadIdx.x;
    int lane = t & 63, wv = t >> 6;
    int wr = wv >> 1, wc = wv & 1;
    int quad = lane >> 4, ln16 = lane & 15;

    int row0 = by * BM;
    int col0 = bx * 128;

    const f32x4 zero4 = {0.f, 0.f, 0.f, 0.f};
    f32x4 acc[MI][4];
    #pragma unroll
    for (int i = 0; i < MI; ++i)
        #pragma unroll
        for (int j = 0; j < 4; ++j) acc[i][j] = zero4;

    auto stage = [&](ushort_t* AsB, ushort_t* BsB, int kt) {
        #pragma unroll
        for (int c = 0; c < BM / 32; ++c) {
            int idx = c * 256 + t;
            int r = idx >> 3, ch = idx & 7;
            int g = ch ^ (r & 7);
            gld16(A + (size_t)(row0 + r) * K + kt + g * 8,
                  AsB + (size_t)(c * 256 + wv * 64) * 8);
        }
        #pragma unroll
        for (int c = 0; c < 4; ++c) {
            int idx = c * 256 + t;
            int r = idx >> 3, ch = idx & 7;
            int g = ch ^ (r & 7);
            gld16(Bt + (size_t)(col0 + r) * K + kt + g * 8,
                  BsB + (size_t)(c * 256 + wv * 64) * 8);
        }
    };

    auto compute = [&](const ushort_t* AsB, const ushort_t* BsB) {
        #pragma unroll
        for (int s = 0; s < 2; ++s) {
            bf16x8 af[MI], bf[4];
            int g = s * 4 + quad;
            #pragma unroll
            for (int i = 0; i < MI; ++i) {
                int m = wr * (BM / 2) + i * 16 + ln16;
                af[i] = *(const bf16x8*)(AsB + (size_t)(m * 8 + (g ^ (m & 7))) * 8);
            }
            #pragma unroll
            for (int j = 0; j < 4; ++j) {
                int n = wc * 64 + j * 16 + ln16;
                bf[j] = *(const bf16x8*)(BsB + (size_t)(n * 8 + (g ^ (n & 7))) * 8);
            }
            __builtin_amdgcn_s_setprio(1);
            #pragma unroll
            for (int i = 0; i < MI; ++i)
                #pragma unroll
                for (int j = 0; j < 4; ++j)
                    acc[i][j] = __builtin_amdgcn_mfma_f32_16x16x32_bf16(
                        af[i], bf[j], acc[i][j], 0, 0, 0);
            __builtin_amdgcn_s_setprio(0);
        }
    };

    auto wait_prev = [&]() {   // tile t's LOADS landed; next tile stays in flight
        if constexpr (BM == 128) asm volatile("s_waitcnt vmcnt(8)" ::: "memory");
        else                     asm volatile("s_waitcnt vmcnt(6)" ::: "memory");
    };

    const int NTk = K / BK;                // 16 (K=1024), even
    stage(As0, Bs0, 0);
    #pragma unroll 1
    for (int it = 0; it < NTk; it += 2) {
        // phase A: compute buf0 (tile it), prefetch tile it+1 into buf1
        stage(As1, Bs1, (it + 1) * BK);    // buf1 reads finished last phase
        wait_prev();
        __builtin_amdgcn_s_barrier();
        __builtin_amdgcn_sched_barrier(0);
        compute(As0, Bs0);
        __builtin_amdgcn_sched_barrier(0);
        __builtin_amdgcn_s_barrier();

        // phase B: compute buf1 (tile it+1), prefetch tile it+2 into buf0
        if (it + 2 < NTk) {
            stage(As0, Bs0, (it + 2) * BK);
            wait_prev();
        } else {
            asm volatile("s_waitcnt vmcnt(0)" ::: "memory");
        }
        __builtin_amdgcn_s_barrier();
        __builtin_amdgcn_sched_barrier(0);
        compute(As1, Bs1);
        __builtin_amdgcn_sched_barrier(0);
        __builtin_amdgcn_s_barrier();
    }

    if (OUT_BF16 && z == 2 && BM == 128) {
        // V^T epilogue: transpose each wave's 64tok x 64ch tile via its own
        // 8KB LDS region (wave-local, no barrier; loop-exit barrier already
        // drained all LDS reads), then coalesced [channel][token] stores.
        ushort_t* tb = Smem + wv * 4096;           // 64 rows x 64 ushorts
        int tok0 = row0 + wr * 64;
        int chn0 = col0 + wc * 64;
        #pragma unroll
        for (int j = 0; j < 4; ++j) {
            int chl = j * 16 + ln16;
            float bv = bias[chn0 + chl];
            #pragma unroll
            for (int i = 0; i < MI; ++i) {
                uint2 uu;
                uu.x = pk2(acc[i][j][0] + bv, acc[i][j][1] + bv);
                uu.y = pk2(acc[i][j][2] + bv, acc[i][j][3] + bv);
                int hc = i * 4 + quad;                  // 8B half-chunk (tok/4)
                int phys = hc ^ ((chl & 7) << 1);       // keeps 16B pairs intact
                *(uint2*)(tb + chl * 64 + phys * 4) = uu;
            }
        }
        int bb2 = tok0 >> 11;
        int tokb = tok0 & 2047;
        #pragma unroll
        for (int p = 0; p < 8; ++p) {
            int chl = p * 8 + (lane >> 3);
            int tc  = lane & 7;
            int ptc = tc ^ (chl & 7);
            uint4 vvv = *(const uint4*)(tb + chl * 64 + ptc * 8);
            *(uint4*)(vt_out + ((size_t)bb2 * 1024 + chn0 + chl) * 2048 + tokb + tc * 8) = vvv;
        }
    } else {
        #pragma unroll
        for (int j = 0; j < 4; ++j) {
            int col = col0 + wc * 64 + j * 16 + ln16;
            float bv = bias[col];
            #pragma unroll
            for (int i = 0; i < MI; ++i) {
                int rowb = row0 + wr * (BM / 2) + i * 16 + quad * 4;
                #pragma unroll
                for (int r = 0; r < 4; ++r) {
                    float val = acc[i][j][r] + bv;
                    if (OUT_BF16) {
                        ushort_t* out = (ushort_t*)out0 + (size_t)z * M * N;
                        out[(size_t)(rowb + r) * N + col] = f2bf(val);
                    } else {
                        float* out = (float*)out0;
                        out[(size_t)(rowb + r) * N + col] = val;
                    }
                }
            }
        }
    }
}

// ---------------------------------------------------------------------------
// MFMA flash attention -- EXACT R7 body (session best: 47.4us), restored
// after the key-split experiments (R8 spilled at the 64-VGPR launch-bounds
// cap; R9 tested cleanly at 80 VGPR and was 23% SLOWER -> LDS-bandwidth
// theory refuted; this structure is the local optimum for 4 waves/block).
// S^T formulation, register-resident P, STATIC softmax, K=32 PV, T15
// two-tile pipeline, KT=64 double-buffered K/V, counted vmcnt(4), T1 XCD
// swizzle, zero4 C-in on first QK s-step, l via ones-MFMA.
// ---------------------------------------------------------------------------
__global__ __launch_bounds__(256, 4) void flash_mfma(
    const ushort_t* __restrict__ qb, const ushort_t* __restrict__ kb,
    const ushort_t* __restrict__ vT, ushort_t* __restrict__ ob)
{
    const int N = 2048, HD = 1024, D = 64, H = 16;
    const int KT = 64;                     // keys per tile
    const int NT = N / KT;                 // 32 tiles
    __shared__ ushort_t Ks[2][64 * 64];    // [buf][perm-pos][d], 8-chunk xor swizzle
    __shared__ ushort_t Vs[2][64 * 64];    // [buf][d][token], 8-chunk xor swizzle

    int t = threadIdx.x, lane = t & 63, wv = t >> 6;
    int quad = lane >> 4, ln16 = lane & 15;
    // T1 XCD swizzle: lin -> chunked remap (1024 = 8 XCDs x 128 chunks).
    int lin = blockIdx.x + 32 * (blockIdx.y + 16 * blockIdx.z);
    int swz = ((lin & 7) << 7) + (lin >> 3);
    int qt = swz & 31, h = (swz >> 5) & 15, b = swz >> 9;

    size_t qk_base = (size_t)b * N * HD + (size_t)h * D;
    size_t vt_base = (size_t)(b * H + h) * D * N;

    // Q fragment (B-operand, K=32) for this wave's 16 rows.
    bf16x8 qf[2];
    {
        const ushort_t* qp = qb + qk_base + (size_t)(qt * 64 + wv * 16 + ln16) * HD;
        qf[0] = *(const bf16x8*)(qp + quad * 8);
        qf[1] = *(const bf16x8*)(qp + 32 + quad * 8);
    }

    // ones fragment (bf16 1.0) for the l-accumulating MFMA.
    bf16x8 ones;
    #pragma unroll
    for (int i = 0; i < 8; ++i) ones[i] = (short)0x3F80;

    const f32x4 zero4 = {0.f, 0.f, 0.f, 0.f};
    f32x4 oacc[4];                         // O^T[d = mt*16+quad*4+r][qrow=ln16]
    f32x4 lacc = zero4;                    // l (all rows identical)
    #pragma unroll
    for (int j = 0; j < 4; ++j) oacc[j] = zero4;

    // ---- staging: 2 gld16 per thread per K-tile / V-tile -------------------
    auto stage_K = [&](ushort_t* KsB, int kt) {
        #pragma unroll
        for (int c = 0; c < 2; ++c) {
            int idx = c * 256 + t;
            int r = idx >> 3, ch = idx & 7, g = ch ^ (r & 7);
            // K row permutation: LDS pos r holds key perm(r)
            int pr = (r & ~31) | (((r >> 2) & 3) << 3) | (((r >> 4) & 1) << 2) | (r & 3);
            gld16(kb + qk_base + (size_t)(kt + pr) * HD + g * 8,
                  KsB + (size_t)(c * 256 + wv * 64) * 8);
        }
    };
    auto stage_V = [&](ushort_t* VsB, int kt) {
        #pragma unroll
        for (int c = 0; c < 2; ++c) {
            int idx = c * 256 + t;
            int r = idx >> 3, ch = idx & 7, g = ch ^ (r & 7);
            gld16(vT + vt_base + (size_t)r * N + kt + g * 8,
                  VsB + (size_t)(c * 256 + wv * 64) * 8);
        }
    };

    // ---- QK^T of one 64-key tile: S^T rows = key pos, cols = qrow ----------
    // s=0 uses zero4 directly as C-in: no per-tile score zero-init movs.
    auto qk_tile = [&](const ushort_t* KsB, f32x4 (&st)[4]) {
        __builtin_amdgcn_s_setprio(1);
        #pragma unroll
        for (int j = 0; j < 4; ++j) {
            int n = j * 16 + ln16;
            bf16x8 kf0 = *(const bf16x8*)(KsB + ((size_t)n * 8 + (quad       ^ (n & 7))) * 8);
            st[j] = __builtin_amdgcn_mfma_f32_16x16x32_bf16(kf0, qf[0], zero4, 0, 0, 0);
        }
        #pragma unroll
        for (int j = 0; j < 4; ++j) {
            int n = j * 16 + ln16;
            bf16x8 kf1 = *(const bf16x8*)(KsB + ((size_t)n * 8 + ((4 + quad) ^ (n & 7))) * 8);
            st[j] = __builtin_amdgcn_mfma_f32_16x16x32_bf16(kf1, qf[1], st[j], 0, 0, 0);
        }
        __builtin_amdgcn_s_setprio(0);
    };

    // ---- softmax + PV of one tile (scores from a PREVIOUS qk_tile) ---------
    auto sm_pv = [&](f32x4 (&st)[4], const ushort_t* VsB) {
        // prefetch all 8 V fragments; their LDS latency hides under exp VALU.
        bf16x8 vf[2][4];
        #pragma unroll
        for (int w = 0; w < 2; ++w) {
            int phys = (w * 4 + quad) ^ (ln16 & 7);
            #pragma unroll
            for (int mt = 0; mt < 4; ++mt)
                vf[w][mt] = *(const bf16x8*)(VsB + (size_t)(mt * 16 + ln16) * 64 + phys * 8);
        }
        // static softmax: p = exp2(s) (q pre-scaled by log2 e).
        #pragma unroll
        for (int j = 0; j < 4; ++j) {
            st[j][0] = fast_exp2(st[j][0]);
            st[j][1] = fast_exp2(st[j][1]);
            st[j][2] = fast_exp2(st[j][2]);
            st[j][3] = fast_exp2(st[j][3]);
        }
        // O^T += V^T @ P (K=32); l += 1 @ P on the matrix pipe.
        #pragma unroll
        for (int w = 0; w < 2; ++w) {
            uint4 up;
            up.x = pk2(st[2*w][0],   st[2*w][1]);
            up.y = pk2(st[2*w][2],   st[2*w][3]);
            up.z = pk2(st[2*w+1][0], st[2*w+1][1]);
            up.w = pk2(st[2*w+1][2], st[2*w+1][3]);
            bf16x8 pf = __builtin_bit_cast(bf16x8, up);
            __builtin_amdgcn_s_setprio(1);
            lacc = __builtin_amdgcn_mfma_f32_16x16x32_bf16(ones, pf, lacc, 0, 0, 0);
            #pragma unroll
            for (int mt = 0; mt < 4; ++mt)
                oacc[mt] = __builtin_amdgcn_mfma_f32_16x16x32_bf16(vf[w][mt], pf, oacc[mt], 0, 0, 0);
            __builtin_amdgcn_s_setprio(0);
        }
    };

    f32x4 stA[4], stB[4];

    // ---- prologue: stage tiles 0,1; compute S(0) ---------------------------
    stage_K(Ks[0], 0);       stage_V(Vs[0], 0);
    stage_K(Ks[1], KT);      stage_V(Vs[1], KT);
    asm volatile("s_waitcnt vmcnt(4)" ::: "memory");   // tile0 K&V landed
    __builtin_amdgcn_s_barrier();
    __builtin_amdgcn_sched_barrier(0);
    qk_tile(Ks[0], stA);                               // S(0)
    __builtin_amdgcn_sched_barrier(0);
    __builtin_amdgcn_s_barrier();                      // all S(0) reads done

    // ---- main loop: phases t = 0..NT-3 (unroll 2, static buffers) ----------
    #pragma unroll 1
    for (int it = 0; it < NT - 2; it += 2) {
        // t = it (even): consume stA/Vs[0], produce stB = S(it+1) from Ks[1]
        stage_K(Ks[0], (it + 2) * KT);                 // K(t) reads done last phase
        asm volatile("s_waitcnt vmcnt(4)" ::: "memory"); // K(it+1), V(it) landed
        __builtin_amdgcn_s_barrier();
        __builtin_amdgcn_sched_barrier(0);
        qk_tile(Ks[1], stB);                           // S(it+1), no dep on stA
        sm_pv(stA, Vs[0]);                             // finish tile it
        __builtin_amdgcn_sched_barrier(0);
        __builtin_amdgcn_s_barrier();                  // all reads this phase done
        stage_V(Vs[0], (it + 2) * KT);                 // V(it) dead -> reuse

        // t = it+1 (odd): consume stB/Vs[1], produce stA = S(it+2) from Ks[0]
        stage_K(Ks[1], (it + 3) * KT);
        asm volatile("s_waitcnt vmcnt(4)" ::: "memory"); // K(it+2), V(it+1) landed
        __builtin_amdgcn_s_barrier();
        __builtin_amdgcn_sched_barrier(0);
        qk_tile(Ks[0], stA);                           // S(it+2)
        sm_pv(stB, Vs[1]);                             // finish tile it+1
        __builtin_amdgcn_sched_barrier(0);
        __builtin_amdgcn_s_barrier();
        stage_V(Vs[1], (it + 3) * KT);
    }

    // ---- tail: t = NT-2 (=30) and t = NT-1 (=31) ---------------------------
    asm volatile("s_waitcnt vmcnt(2)" ::: "memory");   // V(30), K(31) landed
    __builtin_amdgcn_s_barrier();
    __builtin_amdgcn_sched_barrier(0);
    qk_tile(Ks[1], stB);                               // S(31)
    sm_pv(stA, Vs[0]);                                 // tile 30
    asm volatile("s_waitcnt vmcnt(0)" ::: "memory");   // V(31) landed
    __builtin_amdgcn_s_barrier();
    __builtin_amdgcn_sched_barrier(0);
    sm_pv(stB, Vs[1]);                                 // tile 31

    // ---- epilogue: O^T/l, SiLU, packed bf16 stores -------------------------
    // lacc rows are all identical (ones MFMA): no cross-lane reduce needed.
    float inv = 1.0f / lacc[0];
    size_t rowoff = qk_base + (size_t)(qt * 64 + wv * 16 + ln16) * HD;
    #pragma unroll
    for (int mt = 0; mt < 4; ++mt) {
        float o0 = silu_f(oacc[mt][0] * inv);
        float o1 = silu_f(oacc[mt][1] * inv);
        float o2 = silu_f(oacc[mt][2] * inv);
        float o3 = silu_f(oacc[mt][3] * inv);
        uint2 uu;
        uu.x = pk2(o0, o1);
        uu.y = pk2(o2, o3);
        *(uint2*)(ob + rowoff + mt * 16 + quad * 4) = uu;
    }
}

// ---------------------------------------------------------------------------
extern "C" void kernel_launch(void* const* d_in, const int* in_sizes, int n_in,
                              void* d_out, int out_size, void* d_ws, size_t ws_size,
                              hipStream_t stream) {
    const float* x    = (const float*)d_in[0];
    const float* w_q  = (const float*)d_in[1];
    const float* b_q  = (const float*)d_in[2];
    const float* w_k  = (const float*)d_in[3];
    const float* b_k  = (const float*)d_in[4];
    const float* w_v  = (const float*)d_in[5];
    const float* b_v  = (const float*)d_in[6];
    const float* g_q  = (const float*)d_in[7];
    const float* be_q = (const float*)d_in[8];
    const float* g_k  = (const float*)d_in[9];
    const float* be_k = (const float*)d_in[10];
    const float* w_o  = (const float*)d_in[11];
    const float* b_o  = (const float*)d_in[12];
    float* out = (float*)d_out;

    const int B = 2, N = 2048, C = 1024, H = 16, INNER = 1024;
    const int M = B * N;                       // 4096
    const size_t MC = (size_t)M * C;           // 4194304

    // ws layout (ushort elems): sx | qkv(3x, v slot unused) | vT | wT(4x)
    ushort_t* ws  = (ushort_t*)d_ws;
    ushort_t* sx  = ws;                        // [M][1024] bf16 (later reused as o)
    ushort_t* qkv = ws + MC;                   // [3][M][1024]
    ushort_t* vTp = ws + 4 * MC;               // [B][1024][2048] natural key order
    ushort_t* wT  = ws + 5 * MC;               // [4][1024][1024]

    ushort_t* qbuf = qkv;
    ushort_t* kbuf = qkv + MC;
    ushort_t* obuf = sx;                       // sx dead after QKV GEMM

    // 1. fused prelude: weight transposes (blocks 0..1023) + pre-norm SiLU
    //    (blocks 1024..5119) in one launch.
    W4 w4; w4.p[0] = w_q; w4.p[1] = w_k; w4.p[2] = w_v; w4.p[3] = w_o;
    prelude_kernel<<<5120, 256, 0, stream>>>(w4, wT, x, sx);

    // 2. fused QKV GEMM (q/k bf16 rows; v written as natural-order V^T)
    gemm_mfma<128, true><<<dim3(INNER / 128, M / 128, 3), 256, 0, stream>>>(
        sx, wT, b_q, b_k, b_v, qkv, vTp, M, INNER, C);

    // 3. q/k layernorms (bf16 in place); q scaled by inner^-0.5 * log2(e)
    //    (softmax computed in base 2 -> identical weights)
    ln_affine_bf16<<<dim3(M, 2), 256, 0, stream>>>(
        qbuf, kbuf, g_q, be_q, g_k, be_k, 0.03125f * 1.44269504f, 1.0f);

    // 4. flash attention (writes silu(o) bf16 into obuf), 64 Q-rows/block
    flash_mfma<<<dim3(N / 64, H, B), 256, 0, stream>>>(qbuf, kbuf, vTp, obuf);

    // 5. final GEMM -> fp32 out
    gemm_mfma<64, false><<<dim3(C / 128, M / 64, 1), 256, 0, stream>>>(
        obuf, wT + (size_t)3 * 1024 * 1024, b_o, b_o, b_o, out, nullptr, M, C, INNER);
}

// Round 11
// 195.620 us; speedup vs baseline: 1.3814x; 1.0044x over previous
//
#include <hip/hip_runtime.h>
#include <hip/hip_bf16.h>
#include <math.h>

#define LN_EPS 1e-5f

typedef __attribute__((ext_vector_type(8))) short bf16x8;
typedef __attribute__((ext_vector_type(8))) short short8;
typedef __attribute__((ext_vector_type(4))) float f32x4;
typedef unsigned short ushort_t;

__device__ __forceinline__ float silu_f(float x) {
    return x / (1.0f + __expf(-x));
}

__device__ __forceinline__ ushort_t f2bf(float f) {
    __hip_bfloat16 h = __float2bfloat16(f);
    return *reinterpret_cast<ushort_t*>(&h);
}

__device__ __forceinline__ float bf2f(ushort_t u) {
    __hip_bfloat16 h = *reinterpret_cast<__hip_bfloat16*>(&u);
    return __bfloat162float(h);
}

// pack two f32 -> one dword of 2 bf16 (lo = a, hi = b). gfx950 has no
// cvt_pk_bf16 builtin (m240) -- guarantee the single-instruction form.
__device__ __forceinline__ unsigned pk2(float a, float b) {
    unsigned r;
    asm("v_cvt_pk_bf16_f32 %0, %1, %2" : "=v"(r) : "v"(a), "v"(b));
    return r;
}

// exp2 guaranteed as single v_exp_f32.
__device__ __forceinline__ float fast_exp2(float x) {
#if defined(__has_builtin)
#if __has_builtin(__builtin_amdgcn_exp2f)
    return __builtin_amdgcn_exp2f(x);
#else
    return exp2f(x);
#endif
#else
    return exp2f(x);
#endif
}

// async global->LDS 16B per lane. lds must be wave-uniform; dst = lds + lane*16.
__device__ __forceinline__ void gld16(const void* g, void* lds) {
    __builtin_amdgcn_global_load_lds(
        (const __attribute__((address_space(1))) unsigned int*)g,
        (__attribute__((address_space(3))) unsigned int*)lds, 16, 0, 0);
}

// Block-wide reduction of (sum, sumsq). blockDim.x == 256 (4 waves of 64).
__device__ __forceinline__ float2 block_reduce2(float2 p, float2* sbuf) {
    #pragma unroll
    for (int off = 32; off > 0; off >>= 1) {
        p.x += __shfl_down(p.x, off, 64);
        p.y += __shfl_down(p.y, off, 64);
    }
    int lane = threadIdx.x & 63;
    int wid  = threadIdx.x >> 6;
    if (lane == 0) sbuf[wid] = p;
    __syncthreads();
    if (threadIdx.x == 0) {
        float2 r = sbuf[0];
        for (int i = 1; i < 4; ++i) { r.x += sbuf[i].x; r.y += sbuf[i].y; }
        sbuf[0] = r;
    }
    __syncthreads();
    return sbuf[0];
}

// ---------------------------------------------------------------------------
// Fused prelude: blocks 0..1023 transpose the 4 fp32 weight matrices
// [1024][1024] -> bf16 [N][K]; blocks 1024..5119 do LN(no affine) + SiLU on
// x rows (fp32 -> bf16). Data-independent jobs; one launch.
// ---------------------------------------------------------------------------
struct W4 { const float* p[4]; };

__global__ __launch_bounds__(256) void prelude_kernel(
    W4 w, ushort_t* __restrict__ outbase,
    const float* __restrict__ x, ushort_t* __restrict__ xout)
{
    __shared__ float Ls[64][65];
    __shared__ float2 sbuf[4];
    int bid = blockIdx.x;
    int t = threadIdx.x;

    if (bid < 1024) {
        // ---- weight transpose: bid = z*256 + by*16 + bx ----
        int z = bid >> 8;
        const float* in = w.p[z];
        ushort_t* out = outbase + (size_t)z * 1024 * 1024;
        int r0 = ((bid >> 4) & 15) * 64, c0 = (bid & 15) * 64;
        int r = t >> 2, j = (t & 3) * 16;
        #pragma unroll
        for (int i = 0; i < 4; ++i) {
            float4 v = *(const float4*)(in + (size_t)(r0 + r) * 1024 + c0 + j + i * 4);
            Ls[r][j + i*4 + 0] = v.x;
            Ls[r][j + i*4 + 1] = v.y;
            Ls[r][j + i*4 + 2] = v.z;
            Ls[r][j + i*4 + 3] = v.w;
        }
        __syncthreads();
        __align__(16) ushort_t tmp[16];
        #pragma unroll
        for (int i = 0; i < 16; ++i) tmp[i] = f2bf(Ls[j + i][r]);
        ushort_t* op = out + (size_t)(c0 + r) * 1024 + r0 + j;
        *(short8*)(op)     = *(short8*)(tmp);
        *(short8*)(op + 8) = *(short8*)(tmp + 8);
    } else {
        // ---- LN + SiLU on one row of x ----
        const int C = 1024;
        int row = bid - 1024;
        const float4* xr = (const float4*)(x + (size_t)row * C);
        float4 v = xr[t];
        float2 p;
        p.x = v.x + v.y + v.z + v.w;
        p.y = v.x*v.x + v.y*v.y + v.z*v.z + v.w*v.w;
        float2 s = block_reduce2(p, sbuf);
        float mean = s.x / (float)C;
        float var  = s.y / (float)C - mean * mean;
        float rstd = rsqrtf(var + LN_EPS);
        ushort4 y;
        y.x = f2bf(silu_f((v.x - mean) * rstd));
        y.y = f2bf(silu_f((v.y - mean) * rstd));
        y.z = f2bf(silu_f((v.z - mean) * rstd));
        y.w = f2bf(silu_f((v.w - mean) * rstd));
        ((ushort4*)(xout + (size_t)row * C))[t] = y;
    }
}

// ---------------------------------------------------------------------------
// Affine LN in place on bf16 rows of 1024, then scale. grid.y selects q/k.
// ---------------------------------------------------------------------------
__global__ __launch_bounds__(256) void ln_affine_bf16(
    ushort_t* __restrict__ qk0, ushort_t* __restrict__ qk1,
    const float* __restrict__ g0, const float* __restrict__ be0,
    const float* __restrict__ g1, const float* __restrict__ be1,
    float scale0, float scale1)
{
    __shared__ float2 sbuf[4];
    const int C = 1024;
    int which = blockIdx.y;
    ushort_t* q = which ? qk1 : qk0;
    const float* g  = which ? g1  : g0;
    const float* be = which ? be1 : be0;
    float scale = which ? scale1 : scale0;
    int row = blockIdx.x;
    ushort4 u = ((ushort4*)(q + (size_t)row * C))[threadIdx.x];
    float v0 = bf2f(u.x), v1 = bf2f(u.y), v2 = bf2f(u.z), v3 = bf2f(u.w);
    float2 p;
    p.x = v0 + v1 + v2 + v3;
    p.y = v0*v0 + v1*v1 + v2*v2 + v3*v3;
    float2 s = block_reduce2(p, sbuf);
    float mean = s.x / (float)C;
    float var  = s.y / (float)C - mean * mean;
    float rstd = rsqrtf(var + LN_EPS);
    float4 gv = ((const float4*)g)[threadIdx.x];
    float4 bv = ((const float4*)be)[threadIdx.x];
    ushort4 y;
    y.x = f2bf(((v0 - mean) * rstd * gv.x + bv.x) * scale);
    y.y = f2bf(((v1 - mean) * rstd * gv.y + bv.y) * scale);
    y.z = f2bf(((v2 - mean) * rstd * gv.z + bv.z) * scale);
    y.w = f2bf(((v3 - mean) * rstd * gv.w + bv.w) * scale);
    ((ushort4*)(q + (size_t)row * C))[threadIdx.x] = y;
}

// ---------------------------------------------------------------------------
// bf16 MFMA GEMM: C[M,N] = A[M,K] @ Bt[N,K]^T + bias.
// BM x 128 tile, BK=64, 256 threads (4 waves, 2x2), 16x16x32 MFMA.
// Pipelined double-buffered staging (counted vmcnt, raw s_barrier).
// T1 XCD swizzle: bijective chunked remap for L2 locality; launch geometry
// (NY, NZ) is now a template parameter so BM=128 can serve both the QKV
// GEMM (NY=32, NZ=3) and the final GEMM (NY=32, NZ=1 -- this round's
// change: BM 64 -> 128 doubles MFMA-per-ds_read and gives an exact
// 256-block = 1-per-CU grid fit).
// z-grid selects weight/bias (fused QKV). z==2 (V) writes V^T
// [b][channel][token] via a wave-local LDS transpose.
// ---------------------------------------------------------------------------
template<int BM, bool OUT_BF16, int NY, int NZ>
__global__ __launch_bounds__(256) void gemm_mfma(
    const ushort_t* __restrict__ A, const ushort_t* __restrict__ Bt0,
    const float* __restrict__ b0, const float* __restrict__ b1,
    const float* __restrict__ b2, void* __restrict__ out0,
    ushort_t* __restrict__ vt_out,
    int M, int N, int K)
{
    constexpr int BK = 64;
    constexpr int MI = BM / 32;            // m-tiles of 16 per wave
    __shared__ ushort_t Smem[2 * (BM + 128) * BK];
    ushort_t* As0 = Smem;                          // [BM][64]
    ushort_t* Bs0 = Smem + BM * BK;                // [128][64]
    ushort_t* As1 = Smem + (BM + 128) * BK;
    ushort_t* Bs1 = As1 + BM * BK;

    // T1 XCD swizzle. NB % 8 == 0 (bijective chunked remap).
    constexpr int NB = 8 * NY * NZ;
    constexpr int CHUNK = NB / 8;
    int lin = blockIdx.x + 8 * (blockIdx.y + NY * blockIdx.z);
    int swz = (lin & 7) * CHUNK + (lin >> 3);
    int bx = swz & 7;
    int by = (swz >> 3) & (NY - 1);
    int z  = swz / (8 * NY);

    const ushort_t* Bt = Bt0 + (size_t)z * N * K;
    const float* bias = (z == 0) ? b0 : (z == 1) ? b1 : b2;

    int t = threadIdx.x;
    int lane = t & 63, wv = t >> 6;
    int wr = wv >> 1, wc = wv & 1;
    int quad = lane >> 4, ln16 = lane & 15;

    int row0 = by * BM;
    int col0 = bx * 128;

    const f32x4 zero4 = {0.f, 0.f, 0.f, 0.f};
    f32x4 acc[MI][4];
    #pragma unroll
    for (int i = 0; i < MI; ++i)
        #pragma unroll
        for (int j = 0; j < 4; ++j) acc[i][j] = zero4;

    auto stage = [&](ushort_t* AsB, ushort_t* BsB, int kt) {
        #pragma unroll
        for (int c = 0; c < BM / 32; ++c) {
            int idx = c * 256 + t;
            int r = idx >> 3, ch = idx & 7;
            int g = ch ^ (r & 7);
            gld16(A + (size_t)(row0 + r) * K + kt + g * 8,
                  AsB + (size_t)(c * 256 + wv * 64) * 8);
        }
        #pragma unroll
        for (int c = 0; c < 4; ++c) {
            int idx = c * 256 + t;
            int r = idx >> 3, ch = idx & 7;
            int g = ch ^ (r & 7);
            gld16(Bt + (size_t)(col0 + r) * K + kt + g * 8,
                  BsB + (size_t)(c * 256 + wv * 64) * 8);
        }
    };

    auto compute = [&](const ushort_t* AsB, const ushort_t* BsB) {
        #pragma unroll
        for (int s = 0; s < 2; ++s) {
            bf16x8 af[MI], bf[4];
            int g = s * 4 + quad;
            #pragma unroll
            for (int i = 0; i < MI; ++i) {
                int m = wr * (BM / 2) + i * 16 + ln16;
                af[i] = *(const bf16x8*)(AsB + (size_t)(m * 8 + (g ^ (m & 7))) * 8);
            }
            #pragma unroll
            for (int j = 0; j < 4; ++j) {
                int n = wc * 64 + j * 16 + ln16;
                bf[j] = *(const bf16x8*)(BsB + (size_t)(n * 8 + (g ^ (n & 7))) * 8);
            }
            __builtin_amdgcn_s_setprio(1);
            #pragma unroll
            for (int i = 0; i < MI; ++i)
                #pragma unroll
                for (int j = 0; j < 4; ++j)
                    acc[i][j] = __builtin_amdgcn_mfma_f32_16x16x32_bf16(
                        af[i], bf[j], acc[i][j], 0, 0, 0);
            __builtin_amdgcn_s_setprio(0);
        }
    };

    auto wait_prev = [&]() {   // tile t's LOADS landed; next tile stays in flight
        if constexpr (BM == 128) asm volatile("s_waitcnt vmcnt(8)" ::: "memory");
        else                     asm volatile("s_waitcnt vmcnt(6)" ::: "memory");
    };

    const int NTk = K / BK;                // 16 (K=1024), even
    stage(As0, Bs0, 0);
    #pragma unroll 1
    for (int it = 0; it < NTk; it += 2) {
        // phase A: compute buf0 (tile it), prefetch tile it+1 into buf1
        stage(As1, Bs1, (it + 1) * BK);    // buf1 reads finished last phase
        wait_prev();
        __builtin_amdgcn_s_barrier();
        __builtin_amdgcn_sched_barrier(0);
        compute(As0, Bs0);
        __builtin_amdgcn_sched_barrier(0);
        __builtin_amdgcn_s_barrier();

        // phase B: compute buf1 (tile it+1), prefetch tile it+2 into buf0
        if (it + 2 < NTk) {
            stage(As0, Bs0, (it + 2) * BK);
            wait_prev();
        } else {
            asm volatile("s_waitcnt vmcnt(0)" ::: "memory");
        }
        __builtin_amdgcn_s_barrier();
        __builtin_amdgcn_sched_barrier(0);
        compute(As1, Bs1);
        __builtin_amdgcn_sched_barrier(0);
        __builtin_amdgcn_s_barrier();
    }

    if (OUT_BF16 && z == 2 && BM == 128) {
        // V^T epilogue: transpose each wave's 64tok x 64ch tile via its own
        // 8KB LDS region (wave-local, no barrier; loop-exit barrier already
        // drained all LDS reads), then coalesced [channel][token] stores.
        ushort_t* tb = Smem + wv * 4096;           // 64 rows x 64 ushorts
        int tok0 = row0 + wr * 64;
        int chn0 = col0 + wc * 64;
        #pragma unroll
        for (int j = 0; j < 4; ++j) {
            int chl = j * 16 + ln16;
            float bv = bias[chn0 + chl];
            #pragma unroll
            for (int i = 0; i < MI; ++i) {
                uint2 uu;
                uu.x = pk2(acc[i][j][0] + bv, acc[i][j][1] + bv);
                uu.y = pk2(acc[i][j][2] + bv, acc[i][j][3] + bv);
                int hc = i * 4 + quad;                  // 8B half-chunk (tok/4)
                int phys = hc ^ ((chl & 7) << 1);       // keeps 16B pairs intact
                *(uint2*)(tb + chl * 64 + phys * 4) = uu;
            }
        }
        int bb2 = tok0 >> 11;
        int tokb = tok0 & 2047;
        #pragma unroll
        for (int p = 0; p < 8; ++p) {
            int chl = p * 8 + (lane >> 3);
            int tc  = lane & 7;
            int ptc = tc ^ (chl & 7);
            uint4 vvv = *(const uint4*)(tb + chl * 64 + ptc * 8);
            *(uint4*)(vt_out + ((size_t)bb2 * 1024 + chn0 + chl) * 2048 + tokb + tc * 8) = vvv;
        }
    } else {
        #pragma unroll
        for (int j = 0; j < 4; ++j) {
            int col = col0 + wc * 64 + j * 16 + ln16;
            float bv = bias[col];
            #pragma unroll
            for (int i = 0; i < MI; ++i) {
                int rowb = row0 + wr * (BM / 2) + i * 16 + quad * 4;
                #pragma unroll
                for (int r = 0; r < 4; ++r) {
                    float val = acc[i][j][r] + bv;
                    if (OUT_BF16) {
                        ushort_t* out = (ushort_t*)out0 + (size_t)z * M * N;
                        out[(size_t)(rowb + r) * N + col] = f2bf(val);
                    } else {
                        float* out = (float*)out0;
                        out[(size_t)(rowb + r) * N + col] = val;
                    }
                }
            }
        }
    }
}

// ---------------------------------------------------------------------------
// MFMA flash attention -- R7 body (session best: 47.4us). S^T formulation,
// register-resident P, STATIC softmax, K=32 PV, T15 two-tile pipeline,
// KT=64 double-buffered K/V, counted vmcnt(4), T1 XCD swizzle, zero4 C-in
// on first QK s-step, l via ones-MFMA. Key-split refuted (R9: clean test,
// 23% slower); this structure is the local optimum for 4 waves/block.
// ---------------------------------------------------------------------------
__global__ __launch_bounds__(256, 4) void flash_mfma(
    const ushort_t* __restrict__ qb, const ushort_t* __restrict__ kb,
    const ushort_t* __restrict__ vT, ushort_t* __restrict__ ob)
{
    const int N = 2048, HD = 1024, D = 64, H = 16;
    const int KT = 64;                     // keys per tile
    const int NT = N / KT;                 // 32 tiles
    __shared__ ushort_t Ks[2][64 * 64];    // [buf][perm-pos][d], 8-chunk xor swizzle
    __shared__ ushort_t Vs[2][64 * 64];    // [buf][d][token], 8-chunk xor swizzle

    int t = threadIdx.x, lane = t & 63, wv = t >> 6;
    int quad = lane >> 4, ln16 = lane & 15;
    // T1 XCD swizzle: lin -> chunked remap (1024 = 8 XCDs x 128 chunks).
    int lin = blockIdx.x + 32 * (blockIdx.y + 16 * blockIdx.z);
    int swz = ((lin & 7) << 7) + (lin >> 3);
    int qt = swz & 31, h = (swz >> 5) & 15, b = swz >> 9;

    size_t qk_base = (size_t)b * N * HD + (size_t)h * D;
    size_t vt_base = (size_t)(b * H + h) * D * N;

    // Q fragment (B-operand, K=32) for this wave's 16 rows.
    bf16x8 qf[2];
    {
        const ushort_t* qp = qb + qk_base + (size_t)(qt * 64 + wv * 16 + ln16) * HD;
        qf[0] = *(const bf16x8*)(qp + quad * 8);
        qf[1] = *(const bf16x8*)(qp + 32 + quad * 8);
    }

    // ones fragment (bf16 1.0) for the l-accumulating MFMA.
    bf16x8 ones;
    #pragma unroll
    for (int i = 0; i < 8; ++i) ones[i] = (short)0x3F80;

    const f32x4 zero4 = {0.f, 0.f, 0.f, 0.f};
    f32x4 oacc[4];                         // O^T[d = mt*16+quad*4+r][qrow=ln16]
    f32x4 lacc = zero4;                    // l (all rows identical)
    #pragma unroll
    for (int j = 0; j < 4; ++j) oacc[j] = zero4;

    // ---- staging: 2 gld16 per thread per K-tile / V-tile -------------------
    auto stage_K = [&](ushort_t* KsB, int kt) {
        #pragma unroll
        for (int c = 0; c < 2; ++c) {
            int idx = c * 256 + t;
            int r = idx >> 3, ch = idx & 7, g = ch ^ (r & 7);
            // K row permutation: LDS pos r holds key perm(r)
            int pr = (r & ~31) | (((r >> 2) & 3) << 3) | (((r >> 4) & 1) << 2) | (r & 3);
            gld16(kb + qk_base + (size_t)(kt + pr) * HD + g * 8,
                  KsB + (size_t)(c * 256 + wv * 64) * 8);
        }
    };
    auto stage_V = [&](ushort_t* VsB, int kt) {
        #pragma unroll
        for (int c = 0; c < 2; ++c) {
            int idx = c * 256 + t;
            int r = idx >> 3, ch = idx & 7, g = ch ^ (r & 7);
            gld16(vT + vt_base + (size_t)r * N + kt + g * 8,
                  VsB + (size_t)(c * 256 + wv * 64) * 8);
        }
    };

    // ---- QK^T of one 64-key tile: S^T rows = key pos, cols = qrow ----------
    // s=0 uses zero4 directly as C-in: no per-tile score zero-init movs.
    auto qk_tile = [&](const ushort_t* KsB, f32x4 (&st)[4]) {
        __builtin_amdgcn_s_setprio(1);
        #pragma unroll
        for (int j = 0; j < 4; ++j) {
            int n = j * 16 + ln16;
            bf16x8 kf0 = *(const bf16x8*)(KsB + ((size_t)n * 8 + (quad       ^ (n & 7))) * 8);
            st[j] = __builtin_amdgcn_mfma_f32_16x16x32_bf16(kf0, qf[0], zero4, 0, 0, 0);
        }
        #pragma unroll
        for (int j = 0; j < 4; ++j) {
            int n = j * 16 + ln16;
            bf16x8 kf1 = *(const bf16x8*)(KsB + ((size_t)n * 8 + ((4 + quad) ^ (n & 7))) * 8);
            st[j] = __builtin_amdgcn_mfma_f32_16x16x32_bf16(kf1, qf[1], st[j], 0, 0, 0);
        }
        __builtin_amdgcn_s_setprio(0);
    };

    // ---- softmax + PV of one tile (scores from a PREVIOUS qk_tile) ---------
    auto sm_pv = [&](f32x4 (&st)[4], const ushort_t* VsB) {
        // prefetch all 8 V fragments; their LDS latency hides under exp VALU.
        bf16x8 vf[2][4];
        #pragma unroll
        for (int w = 0; w < 2; ++w) {
            int phys = (w * 4 + quad) ^ (ln16 & 7);
            #pragma unroll
            for (int mt = 0; mt < 4; ++mt)
                vf[w][mt] = *(const bf16x8*)(VsB + (size_t)(mt * 16 + ln16) * 64 + phys * 8);
        }
        // static softmax: p = exp2(s) (q pre-scaled by log2 e).
        #pragma unroll
        for (int j = 0; j < 4; ++j) {
            st[j][0] = fast_exp2(st[j][0]);
            st[j][1] = fast_exp2(st[j][1]);
            st[j][2] = fast_exp2(st[j][2]);
            st[j][3] = fast_exp2(st[j][3]);
        }
        // O^T += V^T @ P (K=32); l += 1 @ P on the matrix pipe.
        #pragma unroll
        for (int w = 0; w < 2; ++w) {
            uint4 up;
            up.x = pk2(st[2*w][0],   st[2*w][1]);
            up.y = pk2(st[2*w][2],   st[2*w][3]);
            up.z = pk2(st[2*w+1][0], st[2*w+1][1]);
            up.w = pk2(st[2*w+1][2], st[2*w+1][3]);
            bf16x8 pf = __builtin_bit_cast(bf16x8, up);
            __builtin_amdgcn_s_setprio(1);
            lacc = __builtin_amdgcn_mfma_f32_16x16x32_bf16(ones, pf, lacc, 0, 0, 0);
            #pragma unroll
            for (int mt = 0; mt < 4; ++mt)
                oacc[mt] = __builtin_amdgcn_mfma_f32_16x16x32_bf16(vf[w][mt], pf, oacc[mt], 0, 0, 0);
            __builtin_amdgcn_s_setprio(0);
        }
    };

    f32x4 stA[4], stB[4];

    // ---- prologue: stage tiles 0,1; compute S(0) ---------------------------
    stage_K(Ks[0], 0);       stage_V(Vs[0], 0);
    stage_K(Ks[1], KT);      stage_V(Vs[1], KT);
    asm volatile("s_waitcnt vmcnt(4)" ::: "memory");   // tile0 K&V landed
    __builtin_amdgcn_s_barrier();
    __builtin_amdgcn_sched_barrier(0);
    qk_tile(Ks[0], stA);                               // S(0)
    __builtin_amdgcn_sched_barrier(0);
    __builtin_amdgcn_s_barrier();                      // all S(0) reads done

    // ---- main loop: phases t = 0..NT-3 (unroll 2, static buffers) ----------
    #pragma unroll 1
    for (int it = 0; it < NT - 2; it += 2) {
        // t = it (even): consume stA/Vs[0], produce stB = S(it+1) from Ks[1]
        stage_K(Ks[0], (it + 2) * KT);                 // K(t) reads done last phase
        asm volatile("s_waitcnt vmcnt(4)" ::: "memory"); // K(it+1), V(it) landed
        __builtin_amdgcn_s_barrier();
        __builtin_amdgcn_sched_barrier(0);
        qk_tile(Ks[1], stB);                           // S(it+1), no dep on stA
        sm_pv(stA, Vs[0]);                             // finish tile it
        __builtin_amdgcn_sched_barrier(0);
        __builtin_amdgcn_s_barrier();                  // all reads this phase done
        stage_V(Vs[0], (it + 2) * KT);                 // V(it) dead -> reuse

        // t = it+1 (odd): consume stB/Vs[1], produce stA = S(it+2) from Ks[0]
        stage_K(Ks[1], (it + 3) * KT);
        asm volatile("s_waitcnt vmcnt(4)" ::: "memory"); // K(it+2), V(it+1) landed
        __builtin_amdgcn_s_barrier();
        __builtin_amdgcn_sched_barrier(0);
        qk_tile(Ks[0], stA);                           // S(it+2)
        sm_pv(stB, Vs[1]);                             // finish tile it+1
        __builtin_amdgcn_sched_barrier(0);
        __builtin_amdgcn_s_barrier();
        stage_V(Vs[1], (it + 3) * KT);
    }

    // ---- tail: t = NT-2 (=30) and t = NT-1 (=31) ---------------------------
    asm volatile("s_waitcnt vmcnt(2)" ::: "memory");   // V(30), K(31) landed
    __builtin_amdgcn_s_barrier();
    __builtin_amdgcn_sched_barrier(0);
    qk_tile(Ks[1], stB);                               // S(31)
    sm_pv(stA, Vs[0]);                                 // tile 30
    asm volatile("s_waitcnt vmcnt(0)" ::: "memory");   // V(31) landed
    __builtin_amdgcn_s_barrier();
    __builtin_amdgcn_sched_barrier(0);
    sm_pv(stB, Vs[1]);                                 // tile 31

    // ---- epilogue: O^T/l, SiLU, packed bf16 stores -------------------------
    // lacc rows are all identical (ones MFMA): no cross-lane reduce needed.
    float inv = 1.0f / lacc[0];
    size_t rowoff = qk_base + (size_t)(qt * 64 + wv * 16 + ln16) * HD;
    #pragma unroll
    for (int mt = 0; mt < 4; ++mt) {
        float o0 = silu_f(oacc[mt][0] * inv);
        float o1 = silu_f(oacc[mt][1] * inv);
        float o2 = silu_f(oacc[mt][2] * inv);
        float o3 = silu_f(oacc[mt][3] * inv);
        uint2 uu;
        uu.x = pk2(o0, o1);
        uu.y = pk2(o2, o3);
        *(uint2*)(ob + rowoff + mt * 16 + quad * 4) = uu;
    }
}

// ---------------------------------------------------------------------------
extern "C" void kernel_launch(void* const* d_in, const int* in_sizes, int n_in,
                              void* d_out, int out_size, void* d_ws, size_t ws_size,
                              hipStream_t stream) {
    const float* x    = (const float*)d_in[0];
    const float* w_q  = (const float*)d_in[1];
    const float* b_q  = (const float*)d_in[2];
    const float* w_k  = (const float*)d_in[3];
    const float* b_k  = (const float*)d_in[4];
    const float* w_v  = (const float*)d_in[5];
    const float* b_v  = (const float*)d_in[6];
    const float* g_q  = (const float*)d_in[7];
    const float* be_q = (const float*)d_in[8];
    const float* g_k  = (const float*)d_in[9];
    const float* be_k = (const float*)d_in[10];
    const float* w_o  = (const float*)d_in[11];
    const float* b_o  = (const float*)d_in[12];
    float* out = (float*)d_out;

    const int B = 2, N = 2048, C = 1024, H = 16, INNER = 1024;
    const int M = B * N;                       // 4096
    const size_t MC = (size_t)M * C;           // 4194304

    // ws layout (ushort elems): sx | qkv(3x, v slot unused) | vT | wT(4x)
    ushort_t* ws  = (ushort_t*)d_ws;
    ushort_t* sx  = ws;                        // [M][1024] bf16 (later reused as o)
    ushort_t* qkv = ws + MC;                   // [3][M][1024]
    ushort_t* vTp = ws + 4 * MC;               // [B][1024][2048] natural key order
    ushort_t* wT  = ws + 5 * MC;               // [4][1024][1024]

    ushort_t* qbuf = qkv;
    ushort_t* kbuf = qkv + MC;
    ushort_t* obuf = sx;                       // sx dead after QKV GEMM

    // 1. fused prelude: weight transposes (blocks 0..1023) + pre-norm SiLU
    //    (blocks 1024..5119) in one launch.
    W4 w4; w4.p[0] = w_q; w4.p[1] = w_k; w4.p[2] = w_v; w4.p[3] = w_o;
    prelude_kernel<<<5120, 256, 0, stream>>>(w4, wT, x, sx);

    // 2. fused QKV GEMM (q/k bf16 rows; v written as natural-order V^T)
    gemm_mfma<128, true, 32, 3><<<dim3(INNER / 128, M / 128, 3), 256, 0, stream>>>(
        sx, wT, b_q, b_k, b_v, qkv, vTp, M, INNER, C);

    // 3. q/k layernorms (bf16 in place); q scaled by inner^-0.5 * log2(e)
    //    (softmax computed in base 2 -> identical weights)
    ln_affine_bf16<<<dim3(M, 2), 256, 0, stream>>>(
        qbuf, kbuf, g_q, be_q, g_k, be_k, 0.03125f * 1.44269504f, 1.0f);

    // 4. flash attention (writes silu(o) bf16 into obuf), 64 Q-rows/block
    flash_mfma<<<dim3(N / 64, H, B), 256, 0, stream>>>(qbuf, kbuf, vTp, obuf);

    // 5. final GEMM -> fp32 out (BM=128 this round: MI=4, 256-block grid)
    gemm_mfma<128, false, 32, 1><<<dim3(C / 128, M / 128, 1), 256, 0, stream>>>(
        obuf, wT + (size_t)3 * 1024 * 1024, b_o, b_o, b_o, out, nullptr, M, C, INNER);
}